// Round 2
// baseline (5085.152 us; speedup 1.0000x reference)
//
#include <hip/hip_runtime.h>
#include <math.h>

// Shapes (fixed by the problem): N=50000, E=800000, IN=OUT=128, EA=32, EE=16.
#define TE 32          // edges per block in k_edge_gate
#define BN_EPS 1e-5f

// ---------------------------------------------------------------------------
// K2: scatter-mean numerator + counts.  agg[col[e]] += x[row[e]], cnt[col]++
// One thread handles 4 consecutive floats (float4 read, 4 f32 atomics).
__global__ __launch_bounds__(256) void k_aggregate(
    const float* __restrict__ x, const int* __restrict__ ei,
    float* __restrict__ agg, float* __restrict__ cnt, int N, int E) {
  int total = E * 32;
  for (int idx = blockIdx.x * blockDim.x + threadIdx.x; idx < total;
       idx += gridDim.x * blockDim.x) {
    int e = idx >> 5, c = idx & 31;
    int r = ei[e];
    int d = ei[E + e];
    float4 v = reinterpret_cast<const float4*>(x)[(size_t)r * 32 + c];
    float* dst = agg + (size_t)d * 128 + c * 4;
    unsafeAtomicAdd(dst + 0, v.x);
    unsafeAtomicAdd(dst + 1, v.y);
    unsafeAtomicAdd(dst + 2, v.z);
    unsafeAtomicAdd(dst + 3, v.w);
    if (c == 0) unsafeAtomicAdd(cnt + d, 1.0f);
  }
}

// ---------------------------------------------------------------------------
// K3: out_lin = (agg/max(cnt,1)) @ W_l + x @ W_r + b_l   -> d_out
// Also zeroes agg so the same buffer can be reused as the scatter accumulator.
// Block: 256 threads handles 32 nodes x 128 cols.
__global__ __launch_bounds__(256) void k_node_linear(
    const float* __restrict__ x, float* __restrict__ agg,
    const float* __restrict__ cnt, const float* __restrict__ Wl,
    const float* __restrict__ bl, const float* __restrict__ Wr,
    float* __restrict__ out_lin, int N) {
  __shared__ float a_s[32][128];
  __shared__ float x_s[32][128];
  int n0 = blockIdx.x * 32;
  int tid = threadIdx.x;
#pragma unroll
  for (int i = 0; i < 16; ++i) {
    int idx = tid + i * 256;
    int nl = idx >> 7, j = idx & 127;
    int n = n0 + nl;
    float av = 0.f, xv = 0.f;
    if (n < N) {
      size_t off = (size_t)n * 128 + j;
      float inv = 1.0f / fmaxf(cnt[n], 1.0f);
      av = agg[off] * inv;
      xv = x[off];
      agg[off] = 0.0f;  // re-init as gate-scatter accumulator
    }
    a_s[nl][j] = av;
    x_s[nl][j] = xv;
  }
  __syncthreads();
  int j = tid & 127, g = tid >> 7;  // g in {0,1}: 16 nodes each
  float acc[16];
  float bj = bl[j];
#pragma unroll
  for (int i = 0; i < 16; ++i) acc[i] = bj;
  for (int k = 0; k < 128; ++k) {
    float wl = Wl[k * 128 + j];
    float wr = Wr[k * 128 + j];
#pragma unroll
    for (int i = 0; i < 16; ++i)
      acc[i] += a_s[g * 16 + i][k] * wl + x_s[g * 16 + i][k] * wr;
  }
#pragma unroll
  for (int i = 0; i < 16; ++i) {
    int n = n0 + g * 16 + i;
    if (n < N) out_lin[(size_t)n * 128 + j] = acc[i];
  }
}

// ---------------------------------------------------------------------------
// K4: per-edge pipeline. For a tile of TE=32 edges:
//   emb = relu(ea@W_emb+b_emb); t_attr = ea@W_tattr+b_tattr;
//   t = emb@W_temb+b_temb+t_attr; comb = [out_lin[col], t, t_attr];
//   gate = sigmoid(comb@W_gate+b_gate); acc_out[col] += gate*t (atomic)
__global__ __launch_bounds__(256) void k_edge_gate(
    const float* __restrict__ edge_attr, const int* __restrict__ ei,
    const float* __restrict__ out_lin,
    const float* __restrict__ W_emb, const float* __restrict__ b_emb,
    const float* __restrict__ W_temb, const float* __restrict__ b_temb,
    const float* __restrict__ W_tattr, const float* __restrict__ b_tattr,
    const float* __restrict__ W_gate, const float* __restrict__ b_gate,
    float* __restrict__ acc_out, int E) {
  __shared__ float comb_s[TE][384];  // 48 KB: [out_gather | t | t_attr]
  __shared__ float w_s[32][128];     // 16 KB W_gate chunk
  __shared__ float ea_s[TE][32];     // 4 KB
  __shared__ float emb_s[TE][16];    // 2 KB
  __shared__ int col_s[TE];

  const int tid = threadIdx.x;
  const int e0 = blockIdx.x * TE;

  // stage edge_attr tile + col indices
  {
    int el = tid >> 3, q = tid & 7;
    int e = e0 + el;
    float4 v = make_float4(0.f, 0.f, 0.f, 0.f);
    if (e < E) v = reinterpret_cast<const float4*>(edge_attr)[(size_t)e * 8 + q];
    reinterpret_cast<float4*>(&ea_s[el][0])[q] = v;
    if (tid < TE) {
      int e2 = e0 + tid;
      col_s[tid] = (e2 < E) ? ei[E + e2] : 0;
    }
  }
  __syncthreads();

  // emb tile [TE][16]: 2 outputs per thread
  {
    int o = tid * 2;
    int el = o >> 4, j = o & 15;
    float a0 = b_emb[j], a1 = b_emb[j + 1];
#pragma unroll
    for (int k = 0; k < 32; ++k) {
      float a = ea_s[el][k];
      a0 += a * W_emb[k * 16 + j];
      a1 += a * W_emb[k * 16 + j + 1];
    }
    emb_s[el][j] = fmaxf(a0, 0.f);
    emb_s[el][j + 1] = fmaxf(a1, 0.f);
  }
  __syncthreads();

  const int c4 = tid & 31;  // column quad: cols 4*c4..4*c4+3
  const int eg = tid >> 5;  // edge group: edges eg*4..eg*4+3

  // t_attr, t, gather -> comb_s
  {
    const float4 bta = reinterpret_cast<const float4*>(b_tattr)[c4];
    const float4 btm = reinterpret_cast<const float4*>(b_temb)[c4];
#pragma unroll
    for (int ee = 0; ee < 4; ++ee) {
      int el = eg * 4 + ee;
      float4 ta = bta;
#pragma unroll
      for (int k = 0; k < 32; ++k) {
        float a = ea_s[el][k];
        float4 w = reinterpret_cast<const float4*>(W_tattr + k * 128)[c4];
        ta.x += a * w.x; ta.y += a * w.y; ta.z += a * w.z; ta.w += a * w.w;
      }
      float4 t = make_float4(ta.x + btm.x, ta.y + btm.y, ta.z + btm.z, ta.w + btm.w);
#pragma unroll
      for (int k = 0; k < 16; ++k) {
        float m = emb_s[el][k];
        float4 w = reinterpret_cast<const float4*>(W_temb + k * 128)[c4];
        t.x += m * w.x; t.y += m * w.y; t.z += m * w.z; t.w += m * w.w;
      }
      int cd = col_s[el];
      float4 og = reinterpret_cast<const float4*>(out_lin + (size_t)cd * 128)[c4];
      *reinterpret_cast<float4*>(&comb_s[el][c4 * 4]) = og;
      *reinterpret_cast<float4*>(&comb_s[el][128 + c4 * 4]) = t;
      *reinterpret_cast<float4*>(&comb_s[el][256 + c4 * 4]) = ta;
    }
  }
  __syncthreads();

  // GEMM: [32 edges x 384] @ [384 x 128], K chunks of 32 staged in LDS
  float4 acc[4];
  {
    float4 bg = reinterpret_cast<const float4*>(b_gate)[c4];
#pragma unroll
    for (int ee = 0; ee < 4; ++ee) acc[ee] = bg;
  }
  for (int kc = 0; kc < 12; ++kc) {
    __syncthreads();
#pragma unroll
    for (int i = 0; i < 4; ++i) {
      int idx = tid + i * 256;  // 1024 float4 per chunk
      reinterpret_cast<float4*>(&w_s[0][0])[idx] =
          reinterpret_cast<const float4*>(W_gate)[kc * 1024 + idx];
    }
    __syncthreads();
#pragma unroll
    for (int kk = 0; kk < 32; ++kk) {
      int k = kc * 32 + kk;
      float4 w = *reinterpret_cast<const float4*>(&w_s[kk][c4 * 4]);
#pragma unroll
      for (int ee = 0; ee < 4; ++ee) {
        float cv = comb_s[eg * 4 + ee][k];
        acc[ee].x += cv * w.x;
        acc[ee].y += cv * w.y;
        acc[ee].z += cv * w.z;
        acc[ee].w += cv * w.w;
      }
    }
  }

  // sigmoid, * t, atomic scatter
#pragma unroll
  for (int ee = 0; ee < 4; ++ee) {
    int el = eg * 4 + ee;
    int e = e0 + el;
    if (e >= E) continue;
    int cd = col_s[el];
    float* dst = acc_out + (size_t)cd * 128 + c4 * 4;
    float4 t = *reinterpret_cast<const float4*>(&comb_s[el][128 + c4 * 4]);
    float g0 = 1.f / (1.f + __expf(-acc[ee].x));
    float g1 = 1.f / (1.f + __expf(-acc[ee].y));
    float g2 = 1.f / (1.f + __expf(-acc[ee].z));
    float g3 = 1.f / (1.f + __expf(-acc[ee].w));
    unsafeAtomicAdd(dst + 0, g0 * t.x);
    unsafeAtomicAdd(dst + 1, g1 * t.y);
    unsafeAtomicAdd(dst + 2, g2 * t.z);
    unsafeAtomicAdd(dst + 3, g3 * t.w);
  }
}

// ---------------------------------------------------------------------------
// K5: per-channel sum and sumsq of (out_lin + acc) over N rows.
__global__ __launch_bounds__(256) void k_bn_stats(
    const float* __restrict__ out_lin, const float* __restrict__ acc,
    float* __restrict__ bn, int N) {
  int j = threadIdx.x & 127;
  int g = threadIdx.x >> 7;
  float s = 0.f, s2 = 0.f;
  for (int n = blockIdx.x * 2 + g; n < N; n += gridDim.x * 2) {
    size_t off = (size_t)n * 128 + j;
    float v = out_lin[off] + acc[off];
    s += v;
    s2 += v * v;
  }
  unsafeAtomicAdd(&bn[j], s);
  unsafeAtomicAdd(&bn[128 + j], s2);
}

// ---------------------------------------------------------------------------
// K6: out = relu(2 * ((v - mu)*rsqrt(var+eps)*gamma + beta)), in-place.
__global__ __launch_bounds__(256) void k_finalize(
    float* __restrict__ out, const float* __restrict__ acc,
    const float* __restrict__ bn, const float* __restrict__ gamma,
    const float* __restrict__ beta, int N) {
  int total = N * 32;
  float invN = 1.0f / (float)N;
  for (int idx = blockIdx.x * blockDim.x + threadIdx.x; idx < total;
       idx += gridDim.x * blockDim.x) {
    int q = idx & 31;
    float4 v = reinterpret_cast<float4*>(out)[idx];
    float4 a = reinterpret_cast<const float4*>(acc)[idx];
    float* vp = &v.x;
    const float* ap = &a.x;
    float4 r;
    float* rp = &r.x;
#pragma unroll
    for (int c = 0; c < 4; ++c) {
      int j = q * 4 + c;
      float mu = bn[j] * invN;
      float var = bn[128 + j] * invN - mu * mu;
      float val = vp[c] + ap[c];
      float y = (val - mu) * rsqrtf(var + BN_EPS) * gamma[j] + beta[j];
      rp[c] = fmaxf(2.f * y, 0.f);
    }
    reinterpret_cast<float4*>(out)[idx] = r;
  }
}

// ---------------------------------------------------------------------------
extern "C" void kernel_launch(void* const* d_in, const int* in_sizes, int n_in,
                              void* d_out, int out_size, void* d_ws, size_t ws_size,
                              hipStream_t stream) {
  const float* x       = (const float*)d_in[0];
  const float* ea      = (const float*)d_in[1];
  const float* W_emb   = (const float*)d_in[2];
  const float* b_emb   = (const float*)d_in[3];
  const float* W_temb  = (const float*)d_in[4];
  const float* b_temb  = (const float*)d_in[5];
  const float* W_tattr = (const float*)d_in[6];
  const float* b_tattr = (const float*)d_in[7];
  const float* W_gate  = (const float*)d_in[8];
  const float* b_gate  = (const float*)d_in[9];
  const float* W_l     = (const float*)d_in[10];
  const float* b_l     = (const float*)d_in[11];
  const float* W_r     = (const float*)d_in[12];
  const float* gamma   = (const float*)d_in[13];
  const float* beta    = (const float*)d_in[14];
  const int*   eidx    = (const int*)d_in[15];

  int N = in_sizes[0] / 128;
  int E = in_sizes[1] / 32;

  float* agg = (float*)d_ws;             // N*128 floats; later reused as acc
  float* cnt = agg + (size_t)N * 128;    // N floats
  float* bn  = cnt + N;                  // 256 floats
  float* out = (float*)d_out;

  size_t zero_bytes = ((size_t)N * 128 + N + 256) * sizeof(float);
  hipMemsetAsync(d_ws, 0, zero_bytes, stream);

  k_aggregate<<<2048, 256, 0, stream>>>(x, eidx, agg, cnt, N, E);
  k_node_linear<<<(N + 31) / 32, 256, 0, stream>>>(x, agg, cnt, W_l, b_l, W_r, out, N);
  k_edge_gate<<<(E + TE - 1) / TE, 256, 0, stream>>>(
      ea, eidx, out, W_emb, b_emb, W_temb, b_temb, W_tattr, b_tattr, W_gate,
      b_gate, agg, E);
  k_bn_stats<<<256, 256, 0, stream>>>(out, agg, bn, N);
  k_finalize<<<2048, 256, 0, stream>>>(out, agg, bn, gamma, beta, N);
}

// Round 5
// 2392.402 us; speedup vs baseline: 2.1255x; 2.1255x over previous
//
#include <hip/hip_runtime.h>
#include <math.h>

// Shapes (fixed): N=50000, E=800000, IN=OUT=128, EA=32, EE=16.
#define BN_EPS 1e-5f

typedef short s16x8 __attribute__((ext_vector_type(8)));
typedef float f32x4 __attribute__((ext_vector_type(4)));
#define MFMA16(a, b, c) __builtin_amdgcn_mfma_f32_16x16x32_bf16(a, b, c, 0, 0, 0)

// fp32 -> bf16 bits, round-to-nearest-even
static __device__ __forceinline__ short f2b(float f) {
  union { float f; unsigned u; } x;
  x.f = f;
  unsigned r = (x.u + 0x7fffu + ((x.u >> 16) & 1u)) >> 16;
  return (short)r;
}

// ---------------------------------------------------------------------------
// K0: transpose weights to bf16 [col][k] layouts for MFMA B-fragments.
// WembT[16][32], WtaT[128][32], WteT[128][32] (k 16..31 zero), WgT[128][384]
__global__ __launch_bounds__(256) void k_prep(
    const float* __restrict__ W_emb, const float* __restrict__ W_tattr,
    const float* __restrict__ W_temb, const float* __restrict__ W_gate,
    short* __restrict__ WembT, short* __restrict__ WtaT,
    short* __restrict__ WteT, short* __restrict__ WgT) {
  int t = blockIdx.x * 256 + threadIdx.x;
  if (t < 512) {
    int c = t >> 5, k = t & 31;
    WembT[t] = f2b(W_emb[k * 16 + c]);
  }
  if (t < 4096) {
    int c = t >> 5, k = t & 31;
    WtaT[t] = f2b(W_tattr[k * 128 + c]);
    WteT[t] = (k < 16) ? f2b(W_temb[k * 128 + c]) : (short)0;
  }
  if (t < 49152) {
    int c = t / 384, k = t % 384;
    WgT[t] = f2b(W_gate[k * 128 + c]);
  }
}

// ---------------------------------------------------------------------------
// K2: scatter-mean numerator + counts.
__global__ __launch_bounds__(256) void k_aggregate(
    const float* __restrict__ x, const int* __restrict__ ei,
    float* __restrict__ agg, float* __restrict__ cnt, int N, int E) {
  int total = E * 32;
  for (int idx = blockIdx.x * blockDim.x + threadIdx.x; idx < total;
       idx += gridDim.x * blockDim.x) {
    int e = idx >> 5, c = idx & 31;
    int r = ei[e];
    int d = ei[E + e];
    float4 v = reinterpret_cast<const float4*>(x)[(size_t)r * 32 + c];
    float* dst = agg + (size_t)d * 128 + c * 4;
    unsafeAtomicAdd(dst + 0, v.x);
    unsafeAtomicAdd(dst + 1, v.y);
    unsafeAtomicAdd(dst + 2, v.z);
    unsafeAtomicAdd(dst + 3, v.w);
    if (c == 0) unsafeAtomicAdd(cnt + d, 1.0f);
  }
}

// ---------------------------------------------------------------------------
// K3: out_lin = (agg/max(cnt,1)) @ W_l + x @ W_r + b_l -> d_out; zeroes agg.
__global__ __launch_bounds__(256) void k_node_linear(
    const float* __restrict__ x, float* __restrict__ agg,
    const float* __restrict__ cnt, const float* __restrict__ Wl,
    const float* __restrict__ bl, const float* __restrict__ Wr,
    float* __restrict__ out_lin, int N) {
  __shared__ float a_s[32][128];
  __shared__ float x_s[32][128];
  int n0 = blockIdx.x * 32;
  int tid = threadIdx.x;
#pragma unroll
  for (int i = 0; i < 16; ++i) {
    int idx = tid + i * 256;
    int nl = idx >> 7, j = idx & 127;
    int n = n0 + nl;
    float av = 0.f, xv = 0.f;
    if (n < N) {
      size_t off = (size_t)n * 128 + j;
      float inv = 1.0f / fmaxf(cnt[n], 1.0f);
      av = agg[off] * inv;
      xv = x[off];
      agg[off] = 0.0f;  // re-init as gate-scatter accumulator
    }
    a_s[nl][j] = av;
    x_s[nl][j] = xv;
  }
  __syncthreads();
  int j = tid & 127, g = tid >> 7;
  float acc[16];
  float bj = bl[j];
#pragma unroll
  for (int i = 0; i < 16; ++i) acc[i] = bj;
  for (int k = 0; k < 128; ++k) {
    float wl = Wl[k * 128 + j];
    float wr = Wr[k * 128 + j];
#pragma unroll
    for (int i = 0; i < 16; ++i)
      acc[i] += a_s[g * 16 + i][k] * wl + x_s[g * 16 + i][k] * wr;
  }
#pragma unroll
  for (int i = 0; i < 16; ++i) {
    int n = n0 + g * 16 + i;
    if (n < N) out_lin[(size_t)n * 128 + j] = acc[i];
  }
}

// ---------------------------------------------------------------------------
// K4: MFMA edge pipeline. 64 edges/block, 4 waves x 16 edges, no barriers
// (all LDS traffic is wave-local). Per wave:
//   A_ea (from global) -> emb MFMA -> LDS transpose -> A_emb
//   t_attr/t MFMAs (D-layout regs) -> LDS comb (bf16, A-layout for gate GEMM)
//   gate GEMM: 8 n-tiles x 12 k-steps, B streamed from L2-resident WgT
//   epilogue: sigmoid, * t (regs), fp32 atomic scatter.
__global__ __launch_bounds__(256, 3) void k_edge_gate_mfma(
    const float* __restrict__ edge_attr, const int* __restrict__ ei,
    const float* __restrict__ out_lin,
    const short* __restrict__ WembT, const float* __restrict__ b_emb,
    const short* __restrict__ WteT, const float* __restrict__ b_temb,
    const short* __restrict__ WtaT, const float* __restrict__ b_tattr,
    const short* __restrict__ WgT, const float* __restrict__ b_gate,
    float* __restrict__ acc_out, int E) {
  __shared__ short emb_s[64][40];    // bf16 emb, k-cols 16..31 zeroed (K pad)
  __shared__ short comb_s[64][264];  // bf16 [t (0-127) | t_attr (128-255) | pad]
  __shared__ int col_s[64];

  const int tid = threadIdx.x;
  const int w = tid >> 6;
  const int l = tid & 63;
  const int m = l & 15;   // A: row / B,D: col
  const int g = l >> 4;   // k-group (A/B) or row-group (D)
  const int e0 = blockIdx.x * 64;
  const int erow = w * 16;  // wave-local edge base

  // wave-local: cols + emb k-pad zeros
  if (l < 16) col_s[erow + l] = ei[E + e0 + erow + l];
  {
    int rr = erow + (l >> 2);
    int cc = 16 + (l & 3) * 4;
    int2 zz = make_int2(0, 0);
    *reinterpret_cast<int2*>(&emb_s[rr][cc]) = zz;
  }

  const f32x4 zf = {0.f, 0.f, 0.f, 0.f};

  // A-frag: edge_attr row (edge erow+m), k = g*8..g*8+7
  s16x8 Aea;
  {
    const float* eap = edge_attr + (size_t)(e0 + erow + m) * 32 + g * 8;
    float4 u0 = *reinterpret_cast<const float4*>(eap);
    float4 u1 = *reinterpret_cast<const float4*>(eap + 4);
    Aea[0] = f2b(u0.x); Aea[1] = f2b(u0.y); Aea[2] = f2b(u0.z); Aea[3] = f2b(u0.w);
    Aea[4] = f2b(u1.x); Aea[5] = f2b(u1.y); Aea[6] = f2b(u1.z); Aea[7] = f2b(u1.w);
  }

  // emb = relu(ea @ W_emb + b_emb)  [16 edges x 16]
  {
    s16x8 Bemb = *reinterpret_cast<const s16x8*>(WembT + m * 32 + g * 8);
    f32x4 Demb = MFMA16(Aea, Bemb, zf);
    float be = b_emb[m];
#pragma unroll
    for (int r = 0; r < 4; ++r)
      emb_s[erow + g * 4 + r][m] = f2b(fmaxf(Demb[r] + be, 0.f));
  }

  // A-frag for emb (D->A transpose via LDS, wave-local)
  s16x8 Aemb = *reinterpret_cast<const s16x8*>(&emb_s[erow + m][g * 8]);

  // t_attr (raw) and t (raw, includes t_attr via C operand)
  f32x4 ta[8], tt[8];
#pragma unroll
  for (int n = 0; n < 8; ++n) {
    s16x8 B = *reinterpret_cast<const s16x8*>(WtaT + (n * 16 + m) * 32 + g * 8);
    ta[n] = MFMA16(Aea, B, zf);
  }
#pragma unroll
  for (int n = 0; n < 8; ++n) {
    s16x8 B = *reinterpret_cast<const s16x8*>(WteT + (n * 16 + m) * 32 + g * 8);
    tt[n] = MFMA16(Aemb, B, ta[n]);
  }
  // add biases; stage bf16 t / t_attr into comb (A-layout rows); keep t in regs
#pragma unroll
  for (int n = 0; n < 8; ++n) {
    float bta = b_tattr[n * 16 + m];
    float bte = b_temb[n * 16 + m];
#pragma unroll
    for (int r = 0; r < 4; ++r) {
      float tav = ta[n][r] + bta;
      float tv = tt[n][r] + bta + bte;
      tt[n][r] = tv;
      comb_s[erow + g * 4 + r][n * 16 + m] = f2b(tv);
      comb_s[erow + g * 4 + r][128 + n * 16 + m] = f2b(tav);
    }
  }

  // gate GEMM A-frags: k 0-127 = out_lin gather (global), 128-383 from LDS
  s16x8 Ag[12];
  {
    int cd = col_s[erow + m];
    const float* op = out_lin + (size_t)cd * 128 + g * 8;
#pragma unroll
    for (int kc = 0; kc < 4; ++kc) {
      float4 v0 = *reinterpret_cast<const float4*>(op + kc * 32);
      float4 v1 = *reinterpret_cast<const float4*>(op + kc * 32 + 4);
      s16x8 a;
      a[0] = f2b(v0.x); a[1] = f2b(v0.y); a[2] = f2b(v0.z); a[3] = f2b(v0.w);
      a[4] = f2b(v1.x); a[5] = f2b(v1.y); a[6] = f2b(v1.z); a[7] = f2b(v1.w);
      Ag[kc] = a;
    }
  }
#pragma unroll
  for (int kc = 0; kc < 8; ++kc)
    Ag[4 + kc] = *reinterpret_cast<const s16x8*>(&comb_s[erow + m][kc * 32 + g * 8]);

  int cdD[4];
#pragma unroll
  for (int r = 0; r < 4; ++r) cdD[r] = col_s[erow + g * 4 + r];

#pragma unroll
  for (int n = 0; n < 8; ++n) {
    f32x4 acc = zf;
    const short* bp = WgT + (n * 16 + m) * 384 + g * 8;
#pragma unroll
    for (int kc = 0; kc < 12; ++kc)
      acc = MFMA16(Ag[kc], *reinterpret_cast<const s16x8*>(bp + kc * 32), acc);
    float bg = b_gate[n * 16 + m];
#pragma unroll
    for (int r = 0; r < 4; ++r) {
      float gate = 1.f / (1.f + __expf(-(acc[r] + bg)));
      unsafeAtomicAdd(acc_out + (size_t)cdD[r] * 128 + n * 16 + m,
                      gate * tt[n][r]);
    }
  }
}

// ---------------------------------------------------------------------------
// K5: per-channel sum and sumsq of (out_lin + acc) over N rows.
__global__ __launch_bounds__(256) void k_bn_stats(
    const float* __restrict__ out_lin, const float* __restrict__ acc,
    float* __restrict__ bn, int N) {
  int j = threadIdx.x & 127;
  int g = threadIdx.x >> 7;
  float s = 0.f, s2 = 0.f;
  for (int n = blockIdx.x * 2 + g; n < N; n += gridDim.x * 2) {
    size_t off = (size_t)n * 128 + j;
    float v = out_lin[off] + acc[off];
    s += v;
    s2 += v * v;
  }
  unsafeAtomicAdd(&bn[j], s);
  unsafeAtomicAdd(&bn[128 + j], s2);
}

// ---------------------------------------------------------------------------
// K6: out = relu(2 * BN(out + acc)), in-place on d_out.
__global__ __launch_bounds__(256) void k_finalize(
    float* __restrict__ out, const float* __restrict__ acc,
    const float* __restrict__ bn, const float* __restrict__ gamma,
    const float* __restrict__ beta, int N) {
  int total = N * 32;
  float invN = 1.0f / (float)N;
  for (int idx = blockIdx.x * blockDim.x + threadIdx.x; idx < total;
       idx += gridDim.x * blockDim.x) {
    int q = idx & 31;
    float4 v = reinterpret_cast<float4*>(out)[idx];
    float4 a = reinterpret_cast<const float4*>(acc)[idx];
    float* vp = &v.x;
    const float* ap = &a.x;
    float4 r;
    float* rp = &r.x;
#pragma unroll
    for (int c = 0; c < 4; ++c) {
      int j = q * 4 + c;
      float mu = bn[j] * invN;
      float var = bn[128 + j] * invN - mu * mu;
      float val = vp[c] + ap[c];
      float y = (val - mu) * rsqrtf(var + BN_EPS) * gamma[j] + beta[j];
      rp[c] = fmaxf(2.f * y, 0.f);
    }
    reinterpret_cast<float4*>(out)[idx] = r;
  }
}

// ---------------------------------------------------------------------------
extern "C" void kernel_launch(void* const* d_in, const int* in_sizes, int n_in,
                              void* d_out, int out_size, void* d_ws, size_t ws_size,
                              hipStream_t stream) {
  const float* x       = (const float*)d_in[0];
  const float* ea      = (const float*)d_in[1];
  const float* W_emb   = (const float*)d_in[2];
  const float* b_emb   = (const float*)d_in[3];
  const float* W_temb  = (const float*)d_in[4];
  const float* b_temb  = (const float*)d_in[5];
  const float* W_tattr = (const float*)d_in[6];
  const float* b_tattr = (const float*)d_in[7];
  const float* W_gate  = (const float*)d_in[8];
  const float* b_gate  = (const float*)d_in[9];
  const float* W_l     = (const float*)d_in[10];
  const float* b_l     = (const float*)d_in[11];
  const float* W_r     = (const float*)d_in[12];
  const float* gamma   = (const float*)d_in[13];
  const float* beta    = (const float*)d_in[14];
  const int*   eidx    = (const int*)d_in[15];

  int N = in_sizes[0] / 128;
  int E = in_sizes[1] / 32;

  float* agg = (float*)d_ws;             // N*128 floats; later reused as acc
  float* cnt = agg + (size_t)N * 128;    // N floats
  float* bn  = cnt + N;                  // 256 floats
  short* wb  = (short*)(bn + 256);       // bf16 weight area
  short* WembT = wb;                     // 512
  short* WtaT  = wb + 512;               // 4096
  short* WteT  = wb + 4608;              // 4096
  short* WgT   = wb + 8704;              // 49152
  float* out = (float*)d_out;

  size_t zero_bytes = ((size_t)N * 128 + N + 256) * sizeof(float);
  hipMemsetAsync(d_ws, 0, zero_bytes, stream);

  k_prep<<<192, 256, 0, stream>>>(W_emb, W_tattr, W_temb, W_gate,
                                  WembT, WtaT, WteT, WgT);
  k_aggregate<<<2048, 256, 0, stream>>>(x, eidx, agg, cnt, N, E);
  k_node_linear<<<(N + 31) / 32, 256, 0, stream>>>(x, agg, cnt, W_l, b_l, W_r, out, N);
  k_edge_gate_mfma<<<E / 64, 256, 0, stream>>>(
      ea, eidx, out, WembT, b_emb, WteT, b_temb, WtaT, b_tattr, WgT, b_gate,
      agg, E);
  k_bn_stats<<<512, 256, 0, stream>>>(out, agg, bn, N);
  k_finalize<<<2048, 256, 0, stream>>>(out, agg, bn, gamma, beta, N);
}

// Round 8
// 1291.851 us; speedup vs baseline: 3.9363x; 1.8519x over previous
//
#include <hip/hip_runtime.h>
#include <math.h>

// Shapes (fixed): N=50000, E=800000, IN=OUT=128, EA=32, EE=16.
#define BN_EPS 1e-5f

typedef short s16x8 __attribute__((ext_vector_type(8)));
typedef float f32x4 __attribute__((ext_vector_type(4)));
#define MFMA16(a, b, c) __builtin_amdgcn_mfma_f32_16x16x32_bf16(a, b, c, 0, 0, 0)

// fp32 -> bf16 bits, round-to-nearest-even
static __device__ __forceinline__ short f2b(float f) {
  union { float f; unsigned u; } x;
  x.f = f;
  unsigned r = (x.u + 0x7fffu + ((x.u >> 16) & 1u)) >> 16;
  return (short)r;
}
static __device__ __forceinline__ float b2f(unsigned bits16) {
  union { unsigned u; float f; } x;
  x.u = bits16 << 16;
  return x.f;
}

// ---------------------------------------------------------------------------
// K0: transpose weights to bf16 [col][k] layouts for MFMA B-fragments.
__global__ __launch_bounds__(256) void k_prep(
    const float* __restrict__ W_emb, const float* __restrict__ W_tattr,
    const float* __restrict__ W_temb, const float* __restrict__ W_gate,
    short* __restrict__ WembT, short* __restrict__ WtaT,
    short* __restrict__ WteT, short* __restrict__ WgT) {
  int t = blockIdx.x * 256 + threadIdx.x;
  if (t < 512) {
    int c = t >> 5, k = t & 31;
    WembT[t] = f2b(W_emb[k * 16 + c]);
  }
  if (t < 4096) {
    int c = t >> 5, k = t & 31;
    WtaT[t] = f2b(W_tattr[k * 128 + c]);
    WteT[t] = (k < 16) ? f2b(W_temb[k * 128 + c]) : (short)0;
  }
  if (t < 49152) {
    int c = t / 384, k = t % 384;
    WgT[t] = f2b(W_gate[k * 128 + c]);
  }
}

// ---------------------------------------------------------------------------
// CSR build step 1: per-target counts (int atomics, cheap).
__global__ __launch_bounds__(256) void k_count(
    const int* __restrict__ ei, int* __restrict__ cnt, int E) {
  for (int e = blockIdx.x * blockDim.x + threadIdx.x; e < E;
       e += gridDim.x * blockDim.x)
    atomicAdd(&cnt[ei[E + e]], 1);
}

// CSR build step 2: exclusive scan. Single block, 1024 threads, LDS scan.
// rowptr[0]=0, rowptr[i+1]=incl[i]; wo[i]=excl[i] (fill cursor).
__global__ __launch_bounds__(1024) void k_scan(
    const int* __restrict__ cnt, int* __restrict__ rowptr,
    int* __restrict__ wo, int N) {
  __shared__ int s[1024];
  __shared__ int carry_s;
  int tid = threadIdx.x;
  if (tid == 0) { carry_s = 0; rowptr[0] = 0; }
  __syncthreads();
  for (int base = 0; base < N; base += 1024) {
    int i = base + tid;
    int v = (i < N) ? cnt[i] : 0;
    s[tid] = v;
    __syncthreads();
#pragma unroll
    for (int off = 1; off < 1024; off <<= 1) {
      int t = (tid >= off) ? s[tid - off] : 0;
      __syncthreads();
      s[tid] += t;
      __syncthreads();
    }
    int inc = s[tid] + carry_s;
    if (i < N) { rowptr[i + 1] = inc; wo[i] = inc - v; }
    __syncthreads();
    if (tid == 1023) carry_s = inc;
    __syncthreads();
  }
}

// CSR build step 3: fill. src[pos]=row[e] (source node at CSR slot),
// inv[e]=pos (edge's CSR slot, for the edge-gate streaming write).
__global__ __launch_bounds__(256) void k_fill(
    const int* __restrict__ ei, int* __restrict__ wo,
    int* __restrict__ src, int* __restrict__ inv, int E) {
  for (int e = blockIdx.x * blockDim.x + threadIdx.x; e < E;
       e += gridDim.x * blockDim.x) {
    int c = ei[E + e];
    int p = atomicAdd(&wo[c], 1);
    src[p] = ei[e];
    inv[e] = p;
  }
}

// ---------------------------------------------------------------------------
// K2-CSR: gather-mean. One wave per node; lane l owns cols {2l, 2l+1}.
__global__ __launch_bounds__(256) void k_agg_gather(
    const float* __restrict__ x, const int* __restrict__ rowptr,
    const int* __restrict__ src, float* __restrict__ agg, int N) {
  int node = blockIdx.x * 4 + (threadIdx.x >> 6);
  if (node >= N) return;
  int l = threadIdx.x & 63;
  int s0 = rowptr[node], s1 = rowptr[node + 1];
  float a0 = 0.f, a1 = 0.f;
  int i = s0;
  for (; i + 1 < s1; i += 2) {
    int sa = src[i], sb = src[i + 1];
    float2 va = reinterpret_cast<const float2*>(x + (size_t)sa * 128)[l];
    float2 vb = reinterpret_cast<const float2*>(x + (size_t)sb * 128)[l];
    a0 += va.x + vb.x;
    a1 += va.y + vb.y;
  }
  if (i < s1) {
    float2 va = reinterpret_cast<const float2*>(x + (size_t)src[i] * 128)[l];
    a0 += va.x;
    a1 += va.y;
  }
  float sc = 1.0f / fmaxf((float)(s1 - s0), 1.0f);
  float2 r = make_float2(a0 * sc, a1 * sc);
  reinterpret_cast<float2*>(agg + (size_t)node * 128)[l] = r;
}

// K2-fallback: atomic scatter-mean numerator + counts (round-5 path).
__global__ __launch_bounds__(256) void k_aggregate(
    const float* __restrict__ x, const int* __restrict__ ei,
    float* __restrict__ agg, float* __restrict__ cnt, int N, int E) {
  int total = E * 32;
  for (int idx = blockIdx.x * blockDim.x + threadIdx.x; idx < total;
       idx += gridDim.x * blockDim.x) {
    int e = idx >> 5, c = idx & 31;
    int r = ei[e];
    int d = ei[E + e];
    float4 v = reinterpret_cast<const float4*>(x)[(size_t)r * 32 + c];
    float* dst = agg + (size_t)d * 128 + c * 4;
    unsafeAtomicAdd(dst + 0, v.x);
    unsafeAtomicAdd(dst + 1, v.y);
    unsafeAtomicAdd(dst + 2, v.z);
    unsafeAtomicAdd(dst + 3, v.w);
    if (c == 0) unsafeAtomicAdd(cnt + d, 1.0f);
  }
}

// ---------------------------------------------------------------------------
// K3: out_lin = agg_mean @ W_l + x @ W_r + b_l -> d_out.
// csr=0 fallback: agg is raw sum (divide by cnt) and must be re-zeroed.
__global__ __launch_bounds__(256) void k_node_linear(
    const float* __restrict__ x, float* __restrict__ agg,
    const float* __restrict__ cntf, const float* __restrict__ Wl,
    const float* __restrict__ bl, const float* __restrict__ Wr,
    float* __restrict__ out_lin, int N, int csr) {
  __shared__ float a_s[32][128];
  __shared__ float x_s[32][128];
  int n0 = blockIdx.x * 32;
  int tid = threadIdx.x;
#pragma unroll
  for (int i = 0; i < 16; ++i) {
    int idx = tid + i * 256;
    int nl = idx >> 7, j = idx & 127;
    int n = n0 + nl;
    float av = 0.f, xv = 0.f;
    if (n < N) {
      size_t off = (size_t)n * 128 + j;
      if (csr) {
        av = agg[off];
      } else {
        av = agg[off] / fmaxf(cntf[n], 1.0f);
        agg[off] = 0.0f;  // re-init as gate-scatter accumulator
      }
      xv = x[off];
    }
    a_s[nl][j] = av;
    x_s[nl][j] = xv;
  }
  __syncthreads();
  int j = tid & 127, g = tid >> 7;
  float acc[16];
  float bj = bl[j];
#pragma unroll
  for (int i = 0; i < 16; ++i) acc[i] = bj;
  for (int k = 0; k < 128; ++k) {
    float wl = Wl[k * 128 + j];
    float wr = Wr[k * 128 + j];
#pragma unroll
    for (int i = 0; i < 16; ++i)
      acc[i] += a_s[g * 16 + i][k] * wl + x_s[g * 16 + i][k] * wr;
  }
#pragma unroll
  for (int i = 0; i < 16; ++i) {
    int n = n0 + g * 16 + i;
    if (n < N) out_lin[(size_t)n * 128 + j] = acc[i];
  }
}

// ---------------------------------------------------------------------------
// K4: MFMA edge pipeline. MODE 0: fp32 atomic scatter (fallback).
// MODE 1: stream gate*t as bf16 rows into et[inv[e]] (CSR slot order).
template <int MODE>
__global__ __launch_bounds__(256, 3) void k_edge_gate_mfma(
    const float* __restrict__ edge_attr, const int* __restrict__ ei,
    const float* __restrict__ out_lin,
    const short* __restrict__ WembT, const float* __restrict__ b_emb,
    const short* __restrict__ WteT, const float* __restrict__ b_temb,
    const short* __restrict__ WtaT, const float* __restrict__ b_tattr,
    const short* __restrict__ WgT, const float* __restrict__ b_gate,
    float* __restrict__ acc_out, short* __restrict__ et,
    const int* __restrict__ inv, int E) {
  __shared__ short emb_s[64][40];    // bf16 emb, k-cols 16..31 zeroed (K pad)
  __shared__ short comb_s[64][264];  // bf16 [t | t_attr | pad]
  __shared__ int col_s[64];
  __shared__ int inv_s[64];

  const int tid = threadIdx.x;
  const int w = tid >> 6;
  const int l = tid & 63;
  const int m = l & 15;   // A: row / B,D: col
  const int g = l >> 4;   // k-group (A/B) or row-group (D)
  const int e0 = blockIdx.x * 64;
  const int erow = w * 16;  // wave-local edge base

  if (l < 16) {
    col_s[erow + l] = ei[E + e0 + erow + l];
    if (MODE == 1) inv_s[erow + l] = inv[e0 + erow + l];
  }
  {
    int rr = erow + (l >> 2);
    int cc = 16 + (l & 3) * 4;
    int2 zz = make_int2(0, 0);
    *reinterpret_cast<int2*>(&emb_s[rr][cc]) = zz;
  }

  const f32x4 zf = {0.f, 0.f, 0.f, 0.f};

  // A-frag: edge_attr row (edge erow+m), k = g*8..g*8+7
  s16x8 Aea;
  {
    const float* eap = edge_attr + (size_t)(e0 + erow + m) * 32 + g * 8;
    float4 u0 = *reinterpret_cast<const float4*>(eap);
    float4 u1 = *reinterpret_cast<const float4*>(eap + 4);
    Aea[0] = f2b(u0.x); Aea[1] = f2b(u0.y); Aea[2] = f2b(u0.z); Aea[3] = f2b(u0.w);
    Aea[4] = f2b(u1.x); Aea[5] = f2b(u1.y); Aea[6] = f2b(u1.z); Aea[7] = f2b(u1.w);
  }

  // emb = relu(ea @ W_emb + b_emb)
  {
    s16x8 Bemb = *reinterpret_cast<const s16x8*>(WembT + m * 32 + g * 8);
    f32x4 Demb = MFMA16(Aea, Bemb, zf);
    float be = b_emb[m];
#pragma unroll
    for (int r = 0; r < 4; ++r)
      emb_s[erow + g * 4 + r][m] = f2b(fmaxf(Demb[r] + be, 0.f));
  }

  s16x8 Aemb = *reinterpret_cast<const s16x8*>(&emb_s[erow + m][g * 8]);

  f32x4 ta[8], tt[8];
#pragma unroll
  for (int n = 0; n < 8; ++n) {
    s16x8 B = *reinterpret_cast<const s16x8*>(WtaT + (n * 16 + m) * 32 + g * 8);
    ta[n] = MFMA16(Aea, B, zf);
  }
#pragma unroll
  for (int n = 0; n < 8; ++n) {
    s16x8 B = *reinterpret_cast<const s16x8*>(WteT + (n * 16 + m) * 32 + g * 8);
    tt[n] = MFMA16(Aemb, B, ta[n]);
  }
#pragma unroll
  for (int n = 0; n < 8; ++n) {
    float bta = b_tattr[n * 16 + m];
    float bte = b_temb[n * 16 + m];
#pragma unroll
    for (int r = 0; r < 4; ++r) {
      float tav = ta[n][r] + bta;
      float tv = tt[n][r] + bta + bte;
      tt[n][r] = tv;
      comb_s[erow + g * 4 + r][n * 16 + m] = f2b(tv);
      comb_s[erow + g * 4 + r][128 + n * 16 + m] = f2b(tav);
    }
  }

  // gate GEMM A-frags: k 0-127 = out_lin gather (global), 128-383 from LDS
  s16x8 Ag[12];
  {
    int cd = col_s[erow + m];
    const float* op = out_lin + (size_t)cd * 128 + g * 8;
#pragma unroll
    for (int kc = 0; kc < 4; ++kc) {
      float4 v0 = *reinterpret_cast<const float4*>(op + kc * 32);
      float4 v1 = *reinterpret_cast<const float4*>(op + kc * 32 + 4);
      s16x8 a;
      a[0] = f2b(v0.x); a[1] = f2b(v0.y); a[2] = f2b(v0.z); a[3] = f2b(v0.w);
      a[4] = f2b(v1.x); a[5] = f2b(v1.y); a[6] = f2b(v1.z); a[7] = f2b(v1.w);
      Ag[kc] = a;
    }
  }
#pragma unroll
  for (int kc = 0; kc < 8; ++kc)
    Ag[4 + kc] = *reinterpret_cast<const s16x8*>(&comb_s[erow + m][kc * 32 + g * 8]);

  int dD[4];
#pragma unroll
  for (int r = 0; r < 4; ++r)
    dD[r] = (MODE == 1) ? inv_s[erow + g * 4 + r] : col_s[erow + g * 4 + r];

#pragma unroll
  for (int n = 0; n < 8; ++n) {
    f32x4 acc = zf;
    const short* bp = WgT + (n * 16 + m) * 384 + g * 8;
#pragma unroll
    for (int kc = 0; kc < 12; ++kc)
      acc = MFMA16(Ag[kc], *reinterpret_cast<const s16x8*>(bp + kc * 32), acc);
    float bg = b_gate[n * 16 + m];
#pragma unroll
    for (int r = 0; r < 4; ++r) {
      float gate = 1.f / (1.f + __expf(-(acc[r] + bg)));
      float val = gate * tt[n][r];
      if (MODE == 1) {
        et[(size_t)dD[r] * 128 + n * 16 + m] = f2b(val);
      } else {
        unsafeAtomicAdd(acc_out + (size_t)dD[r] * 128 + n * 16 + m, val);
      }
    }
  }
}

// ---------------------------------------------------------------------------
// K4b (CSR): per node, sum its contiguous et segment; out += sum (in place).
__global__ __launch_bounds__(256) void k_gate_gather(
    const short* __restrict__ et, const int* __restrict__ rowptr,
    float* __restrict__ out, int N) {
  int node = blockIdx.x * 4 + (threadIdx.x >> 6);
  if (node >= N) return;
  int l = threadIdx.x & 63;
  int s0 = rowptr[node], s1 = rowptr[node + 1];
  float a0 = 0.f, a1 = 0.f;
  const unsigned* ep = reinterpret_cast<const unsigned*>(et);
  int i = s0;
  for (; i + 1 < s1; i += 2) {
    unsigned ua = ep[(size_t)i * 64 + l];
    unsigned ub = ep[(size_t)(i + 1) * 64 + l];
    a0 += b2f(ua & 0xffffu) + b2f(ub & 0xffffu);
    a1 += b2f(ua >> 16) + b2f(ub >> 16);
  }
  if (i < s1) {
    unsigned ua = ep[(size_t)i * 64 + l];
    a0 += b2f(ua & 0xffffu);
    a1 += b2f(ua >> 16);
  }
  float2* op = reinterpret_cast<float2*>(out + (size_t)node * 128);
  float2 v = op[l];
  v.x += a0;
  v.y += a1;
  op[l] = v;
}

// ---------------------------------------------------------------------------
// K5: per-channel sum/sumsq. acc==nullptr when out already holds the sum.
__global__ __launch_bounds__(256) void k_bn_stats(
    const float* __restrict__ out_lin, const float* __restrict__ acc,
    float* __restrict__ bn, int N) {
  int j = threadIdx.x & 127;
  int g = threadIdx.x >> 7;
  float s = 0.f, s2 = 0.f;
  for (int n = blockIdx.x * 2 + g; n < N; n += gridDim.x * 2) {
    size_t off = (size_t)n * 128 + j;
    float v = out_lin[off];
    if (acc) v += acc[off];
    s += v;
    s2 += v * v;
  }
  unsafeAtomicAdd(&bn[j], s);
  unsafeAtomicAdd(&bn[128 + j], s2);
}

// ---------------------------------------------------------------------------
// K6: out = relu(2 * BN(val)), in-place. acc==nullptr when out holds the sum.
__global__ __launch_bounds__(256) void k_finalize(
    float* __restrict__ out, const float* __restrict__ acc,
    const float* __restrict__ bn, const float* __restrict__ gamma,
    const float* __restrict__ beta, int N) {
  int total = N * 32;
  float invN = 1.0f / (float)N;
  for (int idx = blockIdx.x * blockDim.x + threadIdx.x; idx < total;
       idx += gridDim.x * blockDim.x) {
    int q = idx & 31;
    float4 v = reinterpret_cast<float4*>(out)[idx];
    float4 a = acc ? reinterpret_cast<const float4*>(acc)[idx]
                   : make_float4(0.f, 0.f, 0.f, 0.f);
    float* vp = &v.x;
    const float* ap = &a.x;
    float4 r;
    float* rp = &r.x;
#pragma unroll
    for (int c = 0; c < 4; ++c) {
      int j = q * 4 + c;
      float mu = bn[j] * invN;
      float var = bn[128 + j] * invN - mu * mu;
      float val = vp[c] + ap[c];
      float y = (val - mu) * rsqrtf(var + BN_EPS) * gamma[j] + beta[j];
      rp[c] = fmaxf(2.f * y, 0.f);
    }
    reinterpret_cast<float4*>(out)[idx] = r;
  }
}

// ---------------------------------------------------------------------------
extern "C" void kernel_launch(void* const* d_in, const int* in_sizes, int n_in,
                              void* d_out, int out_size, void* d_ws, size_t ws_size,
                              hipStream_t stream) {
  const float* x       = (const float*)d_in[0];
  const float* ea      = (const float*)d_in[1];
  const float* W_emb   = (const float*)d_in[2];
  const float* b_emb   = (const float*)d_in[3];
  const float* W_temb  = (const float*)d_in[4];
  const float* b_temb  = (const float*)d_in[5];
  const float* W_tattr = (const float*)d_in[6];
  const float* b_tattr = (const float*)d_in[7];
  const float* W_gate  = (const float*)d_in[8];
  const float* b_gate  = (const float*)d_in[9];
  const float* W_l     = (const float*)d_in[10];
  const float* b_l     = (const float*)d_in[11];
  const float* W_r     = (const float*)d_in[12];
  const float* gamma   = (const float*)d_in[13];
  const float* beta    = (const float*)d_in[14];
  const int*   eidx    = (const int*)d_in[15];

  int N = in_sizes[0] / 128;
  int E = in_sizes[1] / 32;
  float* out = (float*)d_out;
  char* base = (char*)d_ws;

  // --- CSR layout ---
  size_t o = 0;
  auto take = [&](size_t b) { size_t r = o; o = (o + b + 255) & ~(size_t)255; return r; };
  size_t o_agg    = take((size_t)N * 128 * 4);
  size_t o_cnt    = take((size_t)N * 4);
  size_t o_rowptr = take((size_t)(N + 1) * 4);
  size_t o_wo     = take((size_t)N * 4);
  size_t o_src    = take((size_t)E * 4);
  size_t o_inv    = take((size_t)E * 4);
  size_t o_bn     = take(256 * 4);
  size_t o_wb     = take(57856 * 2);
  size_t o_et     = take((size_t)E * 128 * 2);
  bool csr = (ws_size >= o);

  if (csr) {
    float* agg    = (float*)(base + o_agg);
    int*   cnt    = (int*)(base + o_cnt);
    int*   rowptr = (int*)(base + o_rowptr);
    int*   wo     = (int*)(base + o_wo);
    int*   src    = (int*)(base + o_src);
    int*   inv    = (int*)(base + o_inv);
    float* bn     = (float*)(base + o_bn);
    short* wb     = (short*)(base + o_wb);
    short* WembT  = wb;
    short* WtaT   = wb + 512;
    short* WteT   = wb + 4608;
    short* WgT    = wb + 8704;
    short* et     = (short*)(base + o_et);

    hipMemsetAsync(cnt, 0, (size_t)N * 4, stream);
    hipMemsetAsync(bn, 0, 256 * 4, stream);

    k_prep<<<192, 256, 0, stream>>>(W_emb, W_tattr, W_temb, W_gate,
                                    WembT, WtaT, WteT, WgT);
    k_count<<<512, 256, 0, stream>>>(eidx, cnt, E);
    k_scan<<<1, 1024, 0, stream>>>(cnt, rowptr, wo, N);
    k_fill<<<512, 256, 0, stream>>>(eidx, wo, src, inv, E);
    k_agg_gather<<<(N + 3) / 4, 256, 0, stream>>>(x, rowptr, src, agg, N);
    k_node_linear<<<(N + 31) / 32, 256, 0, stream>>>(x, agg, nullptr, W_l, b_l,
                                                     W_r, out, N, 1);
    k_edge_gate_mfma<1><<<E / 64, 256, 0, stream>>>(
        ea, eidx, out, WembT, b_emb, WteT, b_temb, WtaT, b_tattr, WgT, b_gate,
        nullptr, et, inv, E);
    k_gate_gather<<<(N + 3) / 4, 256, 0, stream>>>(et, rowptr, out, N);
    k_bn_stats<<<512, 256, 0, stream>>>(out, nullptr, bn, N);
    k_finalize<<<2048, 256, 0, stream>>>(out, nullptr, bn, gamma, beta, N);
  } else {
    // --- fallback: round-5 atomic path (ws too small for CSR buffers) ---
    float* agg  = (float*)d_ws;
    float* cntf = agg + (size_t)N * 128;
    float* bn   = cntf + N;
    short* wb   = (short*)(bn + 256);
    short* WembT = wb;
    short* WtaT  = wb + 512;
    short* WteT  = wb + 4608;
    short* WgT   = wb + 8704;

    size_t zero_bytes = ((size_t)N * 128 + N + 256) * sizeof(float);
    hipMemsetAsync(d_ws, 0, zero_bytes, stream);

    k_prep<<<192, 256, 0, stream>>>(W_emb, W_tattr, W_temb, W_gate,
                                    WembT, WtaT, WteT, WgT);
    k_aggregate<<<2048, 256, 0, stream>>>(x, eidx, agg, cntf, N, E);
    k_node_linear<<<(N + 31) / 32, 256, 0, stream>>>(x, agg, cntf, W_l, b_l,
                                                     W_r, out, N, 0);
    k_edge_gate_mfma<0><<<E / 64, 256, 0, stream>>>(
        ea, eidx, out, WembT, b_emb, WteT, b_temb, WtaT, b_tattr, WgT, b_gate,
        agg, nullptr, nullptr, E);
    k_bn_stats<<<512, 256, 0, stream>>>(out, agg, bn, N);
    k_finalize<<<2048, 256, 0, stream>>>(out, agg, bn, gamma, beta, N);
  }
}

// Round 10
// 1208.723 us; speedup vs baseline: 4.2070x; 1.0688x over previous
//
#include <hip/hip_runtime.h>
#include <math.h>

// Shapes (fixed): N=50000, E=800000, IN=OUT=128, EA=32, EE=16.
#define BN_EPS 1e-5f

typedef short s16x8 __attribute__((ext_vector_type(8)));
typedef float f32x4 __attribute__((ext_vector_type(4)));
#define MFMA16(a, b, c) __builtin_amdgcn_mfma_f32_16x16x32_bf16(a, b, c, 0, 0, 0)

// fp32 -> bf16 bits, round-to-nearest-even
static __device__ __forceinline__ short f2b(float f) {
  union { float f; unsigned u; } x;
  x.f = f;
  unsigned r = (x.u + 0x7fffu + ((x.u >> 16) & 1u)) >> 16;
  return (short)r;
}
static __device__ __forceinline__ float b2f(unsigned bits16) {
  union { unsigned u; float f; } x;
  x.u = bits16 << 16;
  return x.f;
}

// ---------------------------------------------------------------------------
// K0: bf16 weight prep + gate-weight folding.
//   B1[c][128]  = Wg[0:128]^T              (out part)
//   B23[c][128] = (Wg[128:256]+Wg[256:384])^T   (ta_raw part)
//   Bem[c][32]  = (W_temb @ Wg[128:256])^T, K padded 16->32 with zeros
//   bgf[c] = b_gate + (bta+bte)@Wg2 + bta@Wg3   (fp32)
__global__ __launch_bounds__(256) void k_prep(
    const float* __restrict__ We, const float* __restrict__ Wta,
    const float* __restrict__ Wte, const float* __restrict__ Wg,
    const float* __restrict__ bta, const float* __restrict__ bte,
    const float* __restrict__ bg,
    short* __restrict__ WembT, short* __restrict__ WtaT,
    short* __restrict__ WteT, short* __restrict__ B1,
    short* __restrict__ B23, short* __restrict__ Bem,
    float* __restrict__ bgf) {
  int t = blockIdx.x * 256 + threadIdx.x;
  if (t < 512) {
    int c = t >> 5, k = t & 31;
    WembT[t] = f2b(We[k * 16 + c]);
  }
  if (t < 4096) {
    int c = t >> 5, k = t & 31;
    WtaT[t] = f2b(Wta[k * 128 + c]);
    WteT[t] = (k < 16) ? f2b(Wte[k * 128 + c]) : (short)0;
  }
  if (t < 16384) {
    int c = t >> 7, k = t & 127;
    B1[t] = f2b(Wg[k * 128 + c]);
    B23[t] = f2b(Wg[(128 + k) * 128 + c] + Wg[(256 + k) * 128 + c]);
  }
  if (t < 4096) {
    int c = t >> 5, k = t & 31;
    float s = 0.f;
    if (k < 16)
      for (int j = 0; j < 128; ++j) s += Wte[k * 128 + j] * Wg[(128 + j) * 128 + c];
    Bem[t] = (k < 16) ? f2b(s) : (short)0;
  }
  if (t < 128) {
    float s = bg[t];
    for (int j = 0; j < 128; ++j)
      s += (bta[j] + bte[j]) * Wg[(128 + j) * 128 + t] +
           bta[j] * Wg[(256 + j) * 128 + t];
    bgf[t] = s;
  }
}

// ---------------------------------------------------------------------------
// CSR build step 1: per-target counts (int atomics, cheap).
__global__ __launch_bounds__(256) void k_count(
    const int* __restrict__ ei, int* __restrict__ cnt, int E) {
  for (int e = blockIdx.x * blockDim.x + threadIdx.x; e < E;
       e += gridDim.x * blockDim.x)
    atomicAdd(&cnt[ei[E + e]], 1);
}

// CSR build step 2: exclusive scan. Single block, 1024 threads, LDS scan.
__global__ __launch_bounds__(1024) void k_scan(
    const int* __restrict__ cnt, int* __restrict__ rowptr,
    int* __restrict__ wo, int N) {
  __shared__ int s[1024];
  __shared__ int carry_s;
  int tid = threadIdx.x;
  if (tid == 0) { carry_s = 0; rowptr[0] = 0; }
  __syncthreads();
  for (int base = 0; base < N; base += 1024) {
    int i = base + tid;
    int v = (i < N) ? cnt[i] : 0;
    s[tid] = v;
    __syncthreads();
#pragma unroll
    for (int off = 1; off < 1024; off <<= 1) {
      int t = (tid >= off) ? s[tid - off] : 0;
      __syncthreads();
      s[tid] += t;
      __syncthreads();
    }
    int inc = s[tid] + carry_s;
    if (i < N) { rowptr[i + 1] = inc; wo[i] = inc - v; }
    __syncthreads();
    if (tid == 1023) carry_s = inc;
    __syncthreads();
  }
}

// CSR build step 3: fill. src[pos]=row[e], inv[e]=pos.
__global__ __launch_bounds__(256) void k_fill(
    const int* __restrict__ ei, int* __restrict__ wo,
    int* __restrict__ src, int* __restrict__ inv, int E) {
  for (int e = blockIdx.x * blockDim.x + threadIdx.x; e < E;
       e += gridDim.x * blockDim.x) {
    int c = ei[E + e];
    int p = atomicAdd(&wo[c], 1);
    src[p] = ei[e];
    inv[e] = p;
  }
}

// ---------------------------------------------------------------------------
// K2-CSR: gather-mean. One wave per node; lane l owns cols {2l, 2l+1}.
__global__ __launch_bounds__(256) void k_agg_gather(
    const float* __restrict__ x, const int* __restrict__ rowptr,
    const int* __restrict__ src, float* __restrict__ agg, int N) {
  int node = blockIdx.x * 4 + (threadIdx.x >> 6);
  if (node >= N) return;
  int l = threadIdx.x & 63;
  int s0 = rowptr[node], s1 = rowptr[node + 1];
  float a0 = 0.f, a1 = 0.f;
  int i = s0;
  for (; i + 1 < s1; i += 2) {
    int sa = src[i], sb = src[i + 1];
    float2 va = reinterpret_cast<const float2*>(x + (size_t)sa * 128)[l];
    float2 vb = reinterpret_cast<const float2*>(x + (size_t)sb * 128)[l];
    a0 += va.x + vb.x;
    a1 += va.y + vb.y;
  }
  if (i < s1) {
    float2 va = reinterpret_cast<const float2*>(x + (size_t)src[i] * 128)[l];
    a0 += va.x;
    a1 += va.y;
  }
  float sc = 1.0f / fmaxf((float)(s1 - s0), 1.0f);
  float2 r = make_float2(a0 * sc, a1 * sc);
  reinterpret_cast<float2*>(agg + (size_t)node * 128)[l] = r;
}

// K2-fallback: atomic scatter-mean numerator + counts.
__global__ __launch_bounds__(256) void k_aggregate(
    const float* __restrict__ x, const int* __restrict__ ei,
    float* __restrict__ agg, float* __restrict__ cnt, int N, int E) {
  int total = E * 32;
  for (int idx = blockIdx.x * blockDim.x + threadIdx.x; idx < total;
       idx += gridDim.x * blockDim.x) {
    int e = idx >> 5, c = idx & 31;
    int r = ei[e];
    int d = ei[E + e];
    float4 v = reinterpret_cast<const float4*>(x)[(size_t)r * 32 + c];
    float* dst = agg + (size_t)d * 128 + c * 4;
    unsafeAtomicAdd(dst + 0, v.x);
    unsafeAtomicAdd(dst + 1, v.y);
    unsafeAtomicAdd(dst + 2, v.z);
    unsafeAtomicAdd(dst + 3, v.w);
    if (c == 0) unsafeAtomicAdd(cnt + d, 1.0f);
  }
}

// ---------------------------------------------------------------------------
// K3: out_lin = agg_mean @ W_l + x @ W_r + b_l -> d_out.
__global__ __launch_bounds__(256) void k_node_linear(
    const float* __restrict__ x, float* __restrict__ agg,
    const float* __restrict__ cntf, const float* __restrict__ Wl,
    const float* __restrict__ bl, const float* __restrict__ Wr,
    float* __restrict__ out_lin, int N, int csr) {
  __shared__ float a_s[32][128];
  __shared__ float x_s[32][128];
  int n0 = blockIdx.x * 32;
  int tid = threadIdx.x;
#pragma unroll
  for (int i = 0; i < 16; ++i) {
    int idx = tid + i * 256;
    int nl = idx >> 7, j = idx & 127;
    int n = n0 + nl;
    float av = 0.f, xv = 0.f;
    if (n < N) {
      size_t off = (size_t)n * 128 + j;
      if (csr) {
        av = agg[off];
      } else {
        av = agg[off] / fmaxf(cntf[n], 1.0f);
        agg[off] = 0.0f;
      }
      xv = x[off];
    }
    a_s[nl][j] = av;
    x_s[nl][j] = xv;
  }
  __syncthreads();
  int j = tid & 127, g = tid >> 7;
  float acc[16];
  float bj = bl[j];
#pragma unroll
  for (int i = 0; i < 16; ++i) acc[i] = bj;
  for (int k = 0; k < 128; ++k) {
    float wl = Wl[k * 128 + j];
    float wr = Wr[k * 128 + j];
#pragma unroll
    for (int i = 0; i < 16; ++i)
      acc[i] += a_s[g * 16 + i][k] * wl + x_s[g * 16 + i][k] * wr;
  }
#pragma unroll
  for (int i = 0; i < 16; ++i) {
    int n = n0 + g * 16 + i;
    if (n < N) out_lin[(size_t)n * 128 + j] = acc[i];
  }
}

// ---------------------------------------------------------------------------
// K4: MFMA edge pipeline with folded gate weights.
//   logit = out[col]@B1 + ta_raw@B23 + emb@Bem + bgf
//   MODE 0: fp32 atomic scatter; MODE 1: bf16 stream to et[inv[e]].
template <int MODE>
__global__ __launch_bounds__(256, 4) void k_edge_gate_mfma(
    const float* __restrict__ edge_attr, const int* __restrict__ ei,
    const float* __restrict__ out_lin,
    const short* __restrict__ WembT, const float* __restrict__ b_emb,
    const short* __restrict__ WteT, const float* __restrict__ b_temb,
    const short* __restrict__ WtaT, const float* __restrict__ b_tattr,
    const short* __restrict__ B1, const short* __restrict__ B23,
    const short* __restrict__ Bem, const float* __restrict__ bgf,
    float* __restrict__ acc_out, short* __restrict__ et,
    const int* __restrict__ inv, int E) {
  __shared__ short emb_s[64][40];    // bf16 emb, k 16..31 zeroed (K pad)
  __shared__ short comb_s[64][132];  // bf16 ta_raw rows (A-layout source)
  __shared__ int col_s[64];
  __shared__ int inv_s[64];

  const int tid = threadIdx.x;
  const int w = tid >> 6;
  const int l = tid & 63;
  const int m = l & 15;   // A: row / B,D: col
  const int g = l >> 4;   // k-group (A/B) or row-group (D)
  const int e0 = blockIdx.x * 64;
  const int erow = w * 16;  // wave-local edge base

  if (l < 16) {
    col_s[erow + l] = ei[E + e0 + erow + l];
    if (MODE == 1) inv_s[erow + l] = inv[e0 + erow + l];
  }
  {
    int rr = erow + (l >> 2);
    int cc = 16 + (l & 3) * 4;
    int2 zz = make_int2(0, 0);
    *reinterpret_cast<int2*>(&emb_s[rr][cc]) = zz;
  }

  const f32x4 zf = {0.f, 0.f, 0.f, 0.f};

  // A-frag: edge_attr row (edge erow+m), k = g*8..g*8+7
  s16x8 Aea;
  {
    const float* eap = edge_attr + (size_t)(e0 + erow + m) * 32 + g * 8;
    float4 u0 = *reinterpret_cast<const float4*>(eap);
    float4 u1 = *reinterpret_cast<const float4*>(eap + 4);
    Aea[0] = f2b(u0.x); Aea[1] = f2b(u0.y); Aea[2] = f2b(u0.z); Aea[3] = f2b(u0.w);
    Aea[4] = f2b(u1.x); Aea[5] = f2b(u1.y); Aea[6] = f2b(u1.z); Aea[7] = f2b(u1.w);
  }

  // emb = relu(ea @ W_emb + b_emb)
  {
    s16x8 Bemb = *reinterpret_cast<const s16x8*>(WembT + m * 32 + g * 8);
    f32x4 Demb = MFMA16(Aea, Bemb, zf);
    float be = b_emb[m];
#pragma unroll
    for (int r = 0; r < 4; ++r)
      emb_s[erow + g * 4 + r][m] = f2b(fmaxf(Demb[r] + be, 0.f));
  }

  s16x8 Aemb = *reinterpret_cast<const s16x8*>(&emb_s[erow + m][g * 8]);

  // ta_raw = ea@Wta ; tt_raw = emb@Wte + ta_raw
  f32x4 ta[8], tt[8];
#pragma unroll
  for (int n = 0; n < 8; ++n) {
    s16x8 B = *reinterpret_cast<const s16x8*>(WtaT + (n * 16 + m) * 32 + g * 8);
    ta[n] = MFMA16(Aea, B, zf);
  }
#pragma unroll
  for (int n = 0; n < 8; ++n) {
    s16x8 B = *reinterpret_cast<const s16x8*>(WteT + (n * 16 + m) * 32 + g * 8);
    tt[n] = MFMA16(Aemb, B, ta[n]);
  }
  // stage ta_raw bf16 for A-transpose; finalize t = tt_raw + bta + bte in regs
#pragma unroll
  for (int n = 0; n < 8; ++n) {
    float bta_ = b_tattr[n * 16 + m];
    float bte_ = b_temb[n * 16 + m];
#pragma unroll
    for (int r = 0; r < 4; ++r) {
      comb_s[erow + g * 4 + r][n * 16 + m] = f2b(ta[n][r]);
      tt[n][r] = tt[n][r] + bta_ + bte_;
    }
  }

  // gate A-frags: out_lin gather (4 kc) + ta_raw from LDS (4 kc) + Aemb (1 kc)
  s16x8 Ago[4];
  {
    int cd = col_s[erow + m];
    const float* op = out_lin + (size_t)cd * 128 + g * 8;
#pragma unroll
    for (int kc = 0; kc < 4; ++kc) {
      float4 v0 = *reinterpret_cast<const float4*>(op + kc * 32);
      float4 v1 = *reinterpret_cast<const float4*>(op + kc * 32 + 4);
      s16x8 a;
      a[0] = f2b(v0.x); a[1] = f2b(v0.y); a[2] = f2b(v0.z); a[3] = f2b(v0.w);
      a[4] = f2b(v1.x); a[5] = f2b(v1.y); a[6] = f2b(v1.z); a[7] = f2b(v1.w);
      Ago[kc] = a;
    }
  }
  s16x8 Agt[4];
#pragma unroll
  for (int kc = 0; kc < 4; ++kc)
    Agt[kc] = *reinterpret_cast<const s16x8*>(&comb_s[erow + m][kc * 32 + g * 8]);

  int dD[4];
#pragma unroll
  for (int r = 0; r < 4; ++r)
    dD[r] = (MODE == 1) ? inv_s[erow + g * 4 + r] : col_s[erow + g * 4 + r];

#pragma unroll
  for (int n = 0; n < 8; ++n) {
    const short* b1p = B1 + (n * 16 + m) * 128 + g * 8;
    const short* b23p = B23 + (n * 16 + m) * 128 + g * 8;
    f32x4 acc = zf;
#pragma unroll
    for (int kc = 0; kc < 4; ++kc)
      acc = MFMA16(Ago[kc], *reinterpret_cast<const s16x8*>(b1p + kc * 32), acc);
#pragma unroll
    for (int kc = 0; kc < 4; ++kc)
      acc = MFMA16(Agt[kc], *reinterpret_cast<const s16x8*>(b23p + kc * 32), acc);
    acc = MFMA16(Aemb, *reinterpret_cast<const s16x8*>(Bem + (n * 16 + m) * 32 + g * 8), acc);
    float bg_ = bgf[n * 16 + m];
#pragma unroll
    for (int r = 0; r < 4; ++r) {
      float gate = 1.f / (1.f + __expf(-(acc[r] + bg_)));
      float val = gate * tt[n][r];
      if (MODE == 1) {
        et[(size_t)dD[r] * 128 + n * 16 + m] = f2b(val);
      } else {
        unsafeAtomicAdd(acc_out + (size_t)dD[r] * 128 + n * 16 + m, val);
      }
    }
  }
}

// ---------------------------------------------------------------------------
// K4b (CSR): per node, sum its contiguous et segment; out += sum (in place).
__global__ __launch_bounds__(256) void k_gate_gather(
    const short* __restrict__ et, const int* __restrict__ rowptr,
    float* __restrict__ out, int N) {
  int node = blockIdx.x * 4 + (threadIdx.x >> 6);
  if (node >= N) return;
  int l = threadIdx.x & 63;
  int s0 = rowptr[node], s1 = rowptr[node + 1];
  float a0 = 0.f, a1 = 0.f;
  const unsigned* ep = reinterpret_cast<const unsigned*>(et);
  int i = s0;
  for (; i + 1 < s1; i += 2) {
    unsigned ua = ep[(size_t)i * 64 + l];
    unsigned ub = ep[(size_t)(i + 1) * 64 + l];
    a0 += b2f(ua & 0xffffu) + b2f(ub & 0xffffu);
    a1 += b2f(ua >> 16) + b2f(ub >> 16);
  }
  if (i < s1) {
    unsigned ua = ep[(size_t)i * 64 + l];
    a0 += b2f(ua & 0xffffu);
    a1 += b2f(ua >> 16);
  }
  float2* op = reinterpret_cast<float2*>(out + (size_t)node * 128);
  float2 v = op[l];
  v.x += a0;
  v.y += a1;
  op[l] = v;
}

// ---------------------------------------------------------------------------
// K5: per-channel sum/sumsq. acc==nullptr when out already holds the sum.
__global__ __launch_bounds__(256) void k_bn_stats(
    const float* __restrict__ out_lin, const float* __restrict__ acc,
    float* __restrict__ bn, int N) {
  int j = threadIdx.x & 127;
  int g = threadIdx.x >> 7;
  float s = 0.f, s2 = 0.f;
  for (int n = blockIdx.x * 2 + g; n < N; n += gridDim.x * 2) {
    size_t off = (size_t)n * 128 + j;
    float v = out_lin[off];
    if (acc) v += acc[off];
    s += v;
    s2 += v * v;
  }
  unsafeAtomicAdd(&bn[j], s);
  unsafeAtomicAdd(&bn[128 + j], s2);
}

// ---------------------------------------------------------------------------
// K6: out = relu(2 * BN(val)), in-place.
__global__ __launch_bounds__(256) void k_finalize(
    float* __restrict__ out, const float* __restrict__ acc,
    const float* __restrict__ bn, const float* __restrict__ gamma,
    const float* __restrict__ beta, int N) {
  int total = N * 32;
  float invN = 1.0f / (float)N;
  for (int idx = blockIdx.x * blockDim.x + threadIdx.x; idx < total;
       idx += gridDim.x * blockDim.x) {
    int q = idx & 31;
    float4 v = reinterpret_cast<float4*>(out)[idx];
    float4 a = acc ? reinterpret_cast<const float4*>(acc)[idx]
                   : make_float4(0.f, 0.f, 0.f, 0.f);
    float* vp = &v.x;
    const float* ap = &a.x;
    float4 r;
    float* rp = &r.x;
#pragma unroll
    for (int c = 0; c < 4; ++c) {
      int j = q * 4 + c;
      float mu = bn[j] * invN;
      float var = bn[128 + j] * invN - mu * mu;
      float val = vp[c] + ap[c];
      float y = (val - mu) * rsqrtf(var + BN_EPS) * gamma[j] + beta[j];
      rp[c] = fmaxf(2.f * y, 0.f);
    }
    reinterpret_cast<float4*>(out)[idx] = r;
  }
}

// ---------------------------------------------------------------------------
extern "C" void kernel_launch(void* const* d_in, const int* in_sizes, int n_in,
                              void* d_out, int out_size, void* d_ws, size_t ws_size,
                              hipStream_t stream) {
  const float* x       = (const float*)d_in[0];
  const float* ea      = (const float*)d_in[1];
  const float* W_emb   = (const float*)d_in[2];
  const float* b_emb   = (const float*)d_in[3];
  const float* W_temb  = (const float*)d_in[4];
  const float* b_temb  = (const float*)d_in[5];
  const float* W_tattr = (const float*)d_in[6];
  const float* b_tattr = (const float*)d_in[7];
  const float* W_gate  = (const float*)d_in[8];
  const float* b_gate  = (const float*)d_in[9];
  const float* W_l     = (const float*)d_in[10];
  const float* b_l     = (const float*)d_in[11];
  const float* W_r     = (const float*)d_in[12];
  const float* gamma   = (const float*)d_in[13];
  const float* beta    = (const float*)d_in[14];
  const int*   eidx    = (const int*)d_in[15];

  int N = in_sizes[0] / 128;
  int E = in_sizes[1] / 32;
  float* out = (float*)d_out;
  char* base = (char*)d_ws;

  // weight area: WembT 512 | WtaT 4096 | WteT 4096 | B1 16384 | B23 16384 | Bem 4096
  const size_t WB_SHORTS = 512 + 4096 + 4096 + 16384 + 16384 + 4096;

  size_t o = 0;
  auto take = [&](size_t b) { size_t r = o; o = (o + b + 255) & ~(size_t)255; return r; };
  size_t o_agg    = take((size_t)N * 128 * 4);
  size_t o_cnt    = take((size_t)N * 4);
  size_t o_rowptr = take((size_t)(N + 1) * 4);
  size_t o_wo     = take((size_t)N * 4);
  size_t o_src    = take((size_t)E * 4);
  size_t o_inv    = take((size_t)E * 4);
  size_t o_bn     = take(256 * 4);
  size_t o_wb     = take(WB_SHORTS * 2);
  size_t o_bgf    = take(128 * 4);
  size_t o_et     = take((size_t)E * 128 * 2);
  bool csr = (ws_size >= o);

  if (csr) {
    float* agg    = (float*)(base + o_agg);
    int*   cnt    = (int*)(base + o_cnt);
    int*   rowptr = (int*)(base + o_rowptr);
    int*   wo     = (int*)(base + o_wo);
    int*   src    = (int*)(base + o_src);
    int*   inv    = (int*)(base + o_inv);
    float* bn     = (float*)(base + o_bn);
    short* wb     = (short*)(base + o_wb);
    short* WembT  = wb;
    short* WtaT   = wb + 512;
    short* WteT   = wb + 4608;
    short* B1     = wb + 8704;
    short* B23    = wb + 25088;
    short* Bem    = wb + 41472;
    float* bgf    = (float*)(base + o_bgf);
    short* et     = (short*)(base + o_et);

    hipMemsetAsync(cnt, 0, (size_t)N * 4, stream);
    hipMemsetAsync(bn, 0, 256 * 4, stream);

    k_prep<<<64, 256, 0, stream>>>(W_emb, W_tattr, W_temb, W_gate,
                                   b_tattr, b_temb, b_gate,
                                   WembT, WtaT, WteT, B1, B23, Bem, bgf);
    k_count<<<512, 256, 0, stream>>>(eidx, cnt, E);
    k_scan<<<1, 1024, 0, stream>>>(cnt, rowptr, wo, N);
    k_fill<<<512, 256, 0, stream>>>(eidx, wo, src, inv, E);
    k_agg_gather<<<(N + 3) / 4, 256, 0, stream>>>(x, rowptr, src, agg, N);
    k_node_linear<<<(N + 31) / 32, 256, 0, stream>>>(x, agg, nullptr, W_l, b_l,
                                                     W_r, out, N, 1);
    k_edge_gate_mfma<1><<<E / 64, 256, 0, stream>>>(
        ea, eidx, out, WembT, b_emb, WteT, b_temb, WtaT, b_tattr,
        B1, B23, Bem, bgf, nullptr, et, inv, E);
    k_gate_gather<<<(N + 3) / 4, 256, 0, stream>>>(et, rowptr, out, N);
    k_bn_stats<<<512, 256, 0, stream>>>(out, nullptr, bn, N);
    k_finalize<<<2048, 256, 0, stream>>>(out, nullptr, bn, gamma, beta, N);
  } else {
    // --- fallback: atomic path (ws too small for CSR buffers) ---
    float* agg  = (float*)d_ws;
    float* cntf = agg + (size_t)N * 128;
    float* bn   = cntf + N;
    short* wb   = (short*)(bn + 256);
    short* WembT = wb;
    short* WtaT  = wb + 512;
    short* WteT  = wb + 4608;
    short* B1    = wb + 8704;
    short* B23   = wb + 25088;
    short* Bem   = wb + 41472;
    float* bgf   = (float*)(wb + WB_SHORTS + (WB_SHORTS & 1));

    size_t zero_bytes = ((size_t)N * 128 + N + 256) * sizeof(float);
    hipMemsetAsync(d_ws, 0, zero_bytes, stream);

    k_prep<<<64, 256, 0, stream>>>(W_emb, W_tattr, W_temb, W_gate,
                                   b_tattr, b_temb, b_gate,
                                   WembT, WtaT, WteT, B1, B23, Bem, bgf);
    k_aggregate<<<2048, 256, 0, stream>>>(x, eidx, agg, cntf, N, E);
    k_node_linear<<<(N + 31) / 32, 256, 0, stream>>>(x, agg, cntf, W_l, b_l,
                                                     W_r, out, N, 0);
    k_edge_gate_mfma<0><<<E / 64, 256, 0, stream>>>(
        ea, eidx, out, WembT, b_emb, WteT, b_temb, WtaT, b_tattr,
        B1, B23, Bem, bgf, agg, nullptr, nullptr, E);
    k_bn_stats<<<512, 256, 0, stream>>>(out, agg, bn, N);
    k_finalize<<<2048, 256, 0, stream>>>(out, agg, bn, gamma, beta, N);
  }
}

// Round 16
// 1048.302 us; speedup vs baseline: 4.8508x; 1.1530x over previous
//
#include <hip/hip_runtime.h>
#include <math.h>

// Shapes (fixed): N=50000, E=800000, IN=OUT=128, EA=32, EE=16.
#define BN_EPS 1e-5f

typedef short s16x8 __attribute__((ext_vector_type(8)));
typedef float f32x4 __attribute__((ext_vector_type(4)));
#define MFMA16(a, b, c) __builtin_amdgcn_mfma_f32_16x16x32_bf16(a, b, c, 0, 0, 0)

// fp32 -> bf16 bits, round-to-nearest-even
static __device__ __forceinline__ short f2b(float f) {
  union { float f; unsigned u; } x;
  x.f = f;
  unsigned r = (x.u + 0x7fffu + ((x.u >> 16) & 1u)) >> 16;
  return (short)r;
}
static __device__ __forceinline__ float b2f(unsigned bits16) {
  union { unsigned u; float f; } x;
  x.u = bits16 << 16;
  return x.f;
}

// ---------------------------------------------------------------------------
// K0: bf16 weight prep + gate-weight folding (all folds in fp32, one rounding).
//   B1[c][128]   = Wg[0:128]^T                      (out part)
//   Bta23[c][32] = (W_tattr @ (Wg2+Wg3))^T          (ea part, K=32)
//   Bem[c][32]   = (W_temb @ Wg2)^T, K 16->32 pad   (emb part)
//   bgf[c] = b_gate + (bta+bte)@Wg2 + bta@Wg3
__global__ __launch_bounds__(256) void k_prep(
    const float* __restrict__ We, const float* __restrict__ Wta,
    const float* __restrict__ Wte, const float* __restrict__ Wg,
    const float* __restrict__ bta, const float* __restrict__ bte,
    const float* __restrict__ bg,
    short* __restrict__ WembT, short* __restrict__ WtaT,
    short* __restrict__ WteT, short* __restrict__ B1,
    short* __restrict__ Bta23, short* __restrict__ Bem,
    float* __restrict__ bgf) {
  int t = blockIdx.x * 256 + threadIdx.x;
  if (t < 512) {
    int c = t >> 5, k = t & 31;
    WembT[t] = f2b(We[k * 16 + c]);
  }
  if (t < 4096) {
    int c = t >> 5, k = t & 31;
    WtaT[t] = f2b(Wta[k * 128 + c]);
    WteT[t] = (k < 16) ? f2b(Wte[k * 128 + c]) : (short)0;
  }
  if (t < 16384) {
    int c = t >> 7, k = t & 127;
    B1[t] = f2b(Wg[k * 128 + c]);
  }
  if (t < 4096) {
    int c = t >> 5, k = t & 31;
    // Bta23[c][k] = sum_j Wta[k][j] * (Wg2[j][c] + Wg3[j][c])
    float s = 0.f;
    for (int j = 0; j < 128; ++j)
      s += Wta[k * 128 + j] *
           (Wg[(128 + j) * 128 + c] + Wg[(256 + j) * 128 + c]);
    Bta23[t] = f2b(s);
    // Bem[c][k] = sum_j Wte[k][j] * Wg2[j][c]   (k<16)
    float s2 = 0.f;
    if (k < 16)
      for (int j = 0; j < 128; ++j) s2 += Wte[k * 128 + j] * Wg[(128 + j) * 128 + c];
    Bem[t] = (k < 16) ? f2b(s2) : (short)0;
  }
  if (t < 128) {
    float s = bg[t];
    for (int j = 0; j < 128; ++j)
      s += (bta[j] + bte[j]) * Wg[(128 + j) * 128 + t] +
           bta[j] * Wg[(256 + j) * 128 + t];
    bgf[t] = s;
  }
}

// ---------------------------------------------------------------------------
// CSR build step 1: per-target counts (int atomics, cheap).
__global__ __launch_bounds__(256) void k_count(
    const int* __restrict__ ei, int* __restrict__ cnt, int E) {
  for (int e = blockIdx.x * blockDim.x + threadIdx.x; e < E;
       e += gridDim.x * blockDim.x)
    atomicAdd(&cnt[ei[E + e]], 1);
}

// CSR build step 2: exclusive scan. Single block, 1024 threads, LDS scan.
__global__ __launch_bounds__(1024) void k_scan(
    const int* __restrict__ cnt, int* __restrict__ rowptr,
    int* __restrict__ wo, int N) {
  __shared__ int s[1024];
  __shared__ int carry_s;
  int tid = threadIdx.x;
  if (tid == 0) { carry_s = 0; rowptr[0] = 0; }
  __syncthreads();
  for (int base = 0; base < N; base += 1024) {
    int i = base + tid;
    int v = (i < N) ? cnt[i] : 0;
    s[tid] = v;
    __syncthreads();
#pragma unroll
    for (int off = 1; off < 1024; off <<= 1) {
      int t = (tid >= off) ? s[tid - off] : 0;
      __syncthreads();
      s[tid] += t;
      __syncthreads();
    }
    int inc = s[tid] + carry_s;
    if (i < N) { rowptr[i + 1] = inc; wo[i] = inc - v; }
    __syncthreads();
    if (tid == 1023) carry_s = inc;
    __syncthreads();
  }
}

// CSR build step 3: fill. src[pos]=row[e], inv[e]=pos.
__global__ __launch_bounds__(256) void k_fill(
    const int* __restrict__ ei, int* __restrict__ wo,
    int* __restrict__ src, int* __restrict__ inv, int E) {
  for (int e = blockIdx.x * blockDim.x + threadIdx.x; e < E;
       e += gridDim.x * blockDim.x) {
    int c = ei[E + e];
    int p = atomicAdd(&wo[c], 1);
    src[p] = ei[e];
    inv[e] = p;
  }
}

// ---------------------------------------------------------------------------
// K2-CSR: gather-mean. One wave per node; lane l owns cols {2l, 2l+1}.
__global__ __launch_bounds__(256) void k_agg_gather(
    const float* __restrict__ x, const int* __restrict__ rowptr,
    const int* __restrict__ src, float* __restrict__ agg, int N) {
  int node = blockIdx.x * 4 + (threadIdx.x >> 6);
  if (node >= N) return;
  int l = threadIdx.x & 63;
  int s0 = rowptr[node], s1 = rowptr[node + 1];
  float a0 = 0.f, a1 = 0.f;
  int i = s0;
  for (; i + 1 < s1; i += 2) {
    int sa = src[i], sb = src[i + 1];
    float2 va = reinterpret_cast<const float2*>(x + (size_t)sa * 128)[l];
    float2 vb = reinterpret_cast<const float2*>(x + (size_t)sb * 128)[l];
    a0 += va.x + vb.x;
    a1 += va.y + vb.y;
  }
  if (i < s1) {
    float2 va = reinterpret_cast<const float2*>(x + (size_t)src[i] * 128)[l];
    a0 += va.x;
    a1 += va.y;
  }
  float sc = 1.0f / fmaxf((float)(s1 - s0), 1.0f);
  float2 r = make_float2(a0 * sc, a1 * sc);
  reinterpret_cast<float2*>(agg + (size_t)node * 128)[l] = r;
}

// K2-fallback: atomic scatter-mean numerator + counts.
__global__ __launch_bounds__(256) void k_aggregate(
    const float* __restrict__ x, const int* __restrict__ ei,
    float* __restrict__ agg, float* __restrict__ cnt, int N, int E) {
  int total = E * 32;
  for (int idx = blockIdx.x * blockDim.x + threadIdx.x; idx < total;
       idx += gridDim.x * blockDim.x) {
    int e = idx >> 5, c = idx & 31;
    int r = ei[e];
    int d = ei[E + e];
    float4 v = reinterpret_cast<const float4*>(x)[(size_t)r * 32 + c];
    float* dst = agg + (size_t)d * 128 + c * 4;
    unsafeAtomicAdd(dst + 0, v.x);
    unsafeAtomicAdd(dst + 1, v.y);
    unsafeAtomicAdd(dst + 2, v.z);
    unsafeAtomicAdd(dst + 3, v.w);
    if (c == 0) unsafeAtomicAdd(cnt + d, 1.0f);
  }
}

// ---------------------------------------------------------------------------
// K3: out_lin = agg_mean @ W_l + x @ W_r + b_l -> d_out (+ bf16 copy obf).
__global__ __launch_bounds__(256) void k_node_linear(
    const float* __restrict__ x, float* __restrict__ agg,
    const float* __restrict__ cntf, const float* __restrict__ Wl,
    const float* __restrict__ bl, const float* __restrict__ Wr,
    float* __restrict__ out_lin, short* __restrict__ obf, int N, int csr) {
  __shared__ float a_s[32][128];
  __shared__ float x_s[32][128];
  int n0 = blockIdx.x * 32;
  int tid = threadIdx.x;
#pragma unroll
  for (int i = 0; i < 16; ++i) {
    int idx = tid + i * 256;
    int nl = idx >> 7, j = idx & 127;
    int n = n0 + nl;
    float av = 0.f, xv = 0.f;
    if (n < N) {
      size_t off = (size_t)n * 128 + j;
      if (csr) {
        av = agg[off];
      } else {
        av = agg[off] / fmaxf(cntf[n], 1.0f);
        agg[off] = 0.0f;
      }
      xv = x[off];
    }
    a_s[nl][j] = av;
    x_s[nl][j] = xv;
  }
  __syncthreads();
  int j = tid & 127, g = tid >> 7;
  float acc[16];
  float bj = bl[j];
#pragma unroll
  for (int i = 0; i < 16; ++i) acc[i] = bj;
  for (int k = 0; k < 128; ++k) {
    float wl = Wl[k * 128 + j];
    float wr = Wr[k * 128 + j];
#pragma unroll
    for (int i = 0; i < 16; ++i)
      acc[i] += a_s[g * 16 + i][k] * wl + x_s[g * 16 + i][k] * wr;
  }
#pragma unroll
  for (int i = 0; i < 16; ++i) {
    int n = n0 + g * 16 + i;
    if (n < N) {
      size_t off = (size_t)n * 128 + j;
      out_lin[off] = acc[i];
      if (obf) obf[off] = f2b(acc[i]);
    }
  }
}

// ---------------------------------------------------------------------------
// K4: MFMA edge pipeline, fully folded gate:
//   logit = out[col]@B1 + ea@Bta23 + emb@Bem + bgf
//   t (for epilogue) = ea@Wta + emb@Wte + bta + bte   (D-layout regs)
//   MODE 0: fp32 atomic scatter (fp32 out gather); MODE 1: bf16 et stream
//   (bf16 out gather via obf).
template <int MODE>
__global__ __launch_bounds__(256, 6) void k_edge_gate_mfma(
    const float* __restrict__ edge_attr, const int* __restrict__ ei,
    const float* __restrict__ out_lin, const short* __restrict__ obf,
    const short* __restrict__ WembT, const float* __restrict__ b_emb,
    const short* __restrict__ WteT, const float* __restrict__ b_temb,
    const short* __restrict__ WtaT, const float* __restrict__ b_tattr,
    const short* __restrict__ B1, const short* __restrict__ Bta23,
    const short* __restrict__ Bem, const float* __restrict__ bgf,
    float* __restrict__ acc_out, short* __restrict__ et,
    const int* __restrict__ inv, int E) {
  __shared__ short emb_s[64][40];  // bf16 emb, k 16..31 zeroed (K pad)
  __shared__ int col_s[64];
  __shared__ int inv_s[64];

  const int tid = threadIdx.x;
  const int w = tid >> 6;
  const int l = tid & 63;
  const int m = l & 15;   // A: row / B,D: col
  const int g = l >> 4;   // k-group (A/B) or row-group (D)
  const int e0 = blockIdx.x * 64;
  const int erow = w * 16;  // wave-local edge base

  if (l < 16) {
    col_s[erow + l] = ei[E + e0 + erow + l];
    if (MODE == 1) inv_s[erow + l] = inv[e0 + erow + l];
  }
  {
    int rr = erow + (l >> 2);
    int cc = 16 + (l & 3) * 4;
    int2 zz = make_int2(0, 0);
    *reinterpret_cast<int2*>(&emb_s[rr][cc]) = zz;
  }

  const f32x4 zf = {0.f, 0.f, 0.f, 0.f};

  // A-frag: edge_attr row (edge erow+m), k = g*8..g*8+7
  s16x8 Aea;
  {
    const float* eap = edge_attr + (size_t)(e0 + erow + m) * 32 + g * 8;
    float4 u0 = *reinterpret_cast<const float4*>(eap);
    float4 u1 = *reinterpret_cast<const float4*>(eap + 4);
    Aea[0] = f2b(u0.x); Aea[1] = f2b(u0.y); Aea[2] = f2b(u0.z); Aea[3] = f2b(u0.w);
    Aea[4] = f2b(u1.x); Aea[5] = f2b(u1.y); Aea[6] = f2b(u1.z); Aea[7] = f2b(u1.w);
  }

  // emb = relu(ea @ W_emb + b_emb)
  {
    s16x8 Bemb = *reinterpret_cast<const s16x8*>(WembT + m * 32 + g * 8);
    f32x4 Demb = MFMA16(Aea, Bemb, zf);
    float be = b_emb[m];
#pragma unroll
    for (int r = 0; r < 4; ++r)
      emb_s[erow + g * 4 + r][m] = f2b(fmaxf(Demb[r] + be, 0.f));
  }

  s16x8 Aemb = *reinterpret_cast<const s16x8*>(&emb_s[erow + m][g * 8]);

  // t = ea@Wta + emb@Wte (+biases later), D-layout regs
  f32x4 tt[8];
#pragma unroll
  for (int n = 0; n < 8; ++n) {
    s16x8 B = *reinterpret_cast<const s16x8*>(WtaT + (n * 16 + m) * 32 + g * 8);
    f32x4 ta = MFMA16(Aea, B, zf);
    s16x8 B2 = *reinterpret_cast<const s16x8*>(WteT + (n * 16 + m) * 32 + g * 8);
    tt[n] = MFMA16(Aemb, B2, ta);
  }
#pragma unroll
  for (int n = 0; n < 8; ++n) {
    float badd = b_tattr[n * 16 + m] + b_temb[n * 16 + m];
#pragma unroll
    for (int r = 0; r < 4; ++r) tt[n][r] += badd;
  }

  // gate A-frags: out gather (4 kc)
  s16x8 Ago[4];
  {
    int cd = col_s[erow + m];
    if (MODE == 1) {
      const short* op = obf + (size_t)cd * 128 + g * 8;
#pragma unroll
      for (int kc = 0; kc < 4; ++kc)
        Ago[kc] = *reinterpret_cast<const s16x8*>(op + kc * 32);
    } else {
      const float* op = out_lin + (size_t)cd * 128 + g * 8;
#pragma unroll
      for (int kc = 0; kc < 4; ++kc) {
        float4 v0 = *reinterpret_cast<const float4*>(op + kc * 32);
        float4 v1 = *reinterpret_cast<const float4*>(op + kc * 32 + 4);
        s16x8 a;
        a[0] = f2b(v0.x); a[1] = f2b(v0.y); a[2] = f2b(v0.z); a[3] = f2b(v0.w);
        a[4] = f2b(v1.x); a[5] = f2b(v1.y); a[6] = f2b(v1.z); a[7] = f2b(v1.w);
        Ago[kc] = a;
      }
    }
  }

  int dD[4];
#pragma unroll
  for (int r = 0; r < 4; ++r)
    dD[r] = (MODE == 1) ? inv_s[erow + g * 4 + r] : col_s[erow + g * 4 + r];

#pragma unroll
  for (int n = 0; n < 8; ++n) {
    const short* b1p = B1 + (n * 16 + m) * 128 + g * 8;
    f32x4 acc = zf;
#pragma unroll
    for (int kc = 0; kc < 4; ++kc)
      acc = MFMA16(Ago[kc], *reinterpret_cast<const s16x8*>(b1p + kc * 32), acc);
    acc = MFMA16(Aea, *reinterpret_cast<const s16x8*>(Bta23 + (n * 16 + m) * 32 + g * 8), acc);
    acc = MFMA16(Aemb, *reinterpret_cast<const s16x8*>(Bem + (n * 16 + m) * 32 + g * 8), acc);
    float bg_ = bgf[n * 16 + m];
#pragma unroll
    for (int r = 0; r < 4; ++r) {
      float gate = 1.f / (1.f + __expf(-(acc[r] + bg_)));
      float val = gate * tt[n][r];
      if (MODE == 1) {
        et[(size_t)dD[r] * 128 + n * 16 + m] = f2b(val);
      } else {
        unsafeAtomicAdd(acc_out + (size_t)dD[r] * 128 + n * 16 + m, val);
      }
    }
  }
}

// ---------------------------------------------------------------------------
// K4b (CSR): per node, sum its contiguous et segment; out += sum (in place).
__global__ __launch_bounds__(256) void k_gate_gather(
    const short* __restrict__ et, const int* __restrict__ rowptr,
    float* __restrict__ out, int N) {
  int node = blockIdx.x * 4 + (threadIdx.x >> 6);
  if (node >= N) return;
  int l = threadIdx.x & 63;
  int s0 = rowptr[node], s1 = rowptr[node + 1];
  float a0 = 0.f, a1 = 0.f;
  const unsigned* ep = reinterpret_cast<const unsigned*>(et);
  int i = s0;
  for (; i + 1 < s1; i += 2) {
    unsigned ua = ep[(size_t)i * 64 + l];
    unsigned ub = ep[(size_t)(i + 1) * 64 + l];
    a0 += b2f(ua & 0xffffu) + b2f(ub & 0xffffu);
    a1 += b2f(ua >> 16) + b2f(ub >> 16);
  }
  if (i < s1) {
    unsigned ua = ep[(size_t)i * 64 + l];
    a0 += b2f(ua & 0xffffu);
    a1 += b2f(ua >> 16);
  }
  float2* op = reinterpret_cast<float2*>(out + (size_t)node * 128);
  float2 v = op[l];
  v.x += a0;
  v.y += a1;
  op[l] = v;
}

// ---------------------------------------------------------------------------
// K5: per-channel sum/sumsq. acc==nullptr when out already holds the sum.
__global__ __launch_bounds__(256) void k_bn_stats(
    const float* __restrict__ out_lin, const float* __restrict__ acc,
    float* __restrict__ bn, int N) {
  int j = threadIdx.x & 127;
  int g = threadIdx.x >> 7;
  float s = 0.f, s2 = 0.f;
  for (int n = blockIdx.x * 2 + g; n < N; n += gridDim.x * 2) {
    size_t off = (size_t)n * 128 + j;
    float v = out_lin[off];
    if (acc) v += acc[off];
    s += v;
    s2 += v * v;
  }
  unsafeAtomicAdd(&bn[j], s);
  unsafeAtomicAdd(&bn[128 + j], s2);
}

// ---------------------------------------------------------------------------
// K6: out = relu(2 * BN(val)), in-place.
__global__ __launch_bounds__(256) void k_finalize(
    float* __restrict__ out, const float* __restrict__ acc,
    const float* __restrict__ bn, const float* __restrict__ gamma,
    const float* __restrict__ beta, int N) {
  int total = N * 32;
  float invN = 1.0f / (float)N;
  for (int idx = blockIdx.x * blockDim.x + threadIdx.x; idx < total;
       idx += gridDim.x * blockDim.x) {
    int q = idx & 31;
    float4 v = reinterpret_cast<float4*>(out)[idx];
    float4 a = acc ? reinterpret_cast<const float4*>(acc)[idx]
                   : make_float4(0.f, 0.f, 0.f, 0.f);
    float* vp = &v.x;
    const float* ap = &a.x;
    float4 r;
    float* rp = &r.x;
#pragma unroll
    for (int c = 0; c < 4; ++c) {
      int j = q * 4 + c;
      float mu = bn[j] * invN;
      float var = bn[128 + j] * invN - mu * mu;
      float val = vp[c] + ap[c];
      float y = (val - mu) * rsqrtf(var + BN_EPS) * gamma[j] + beta[j];
      rp[c] = fmaxf(2.f * y, 0.f);
    }
    reinterpret_cast<float4*>(out)[idx] = r;
  }
}

// ---------------------------------------------------------------------------
extern "C" void kernel_launch(void* const* d_in, const int* in_sizes, int n_in,
                              void* d_out, int out_size, void* d_ws, size_t ws_size,
                              hipStream_t stream) {
  const float* x       = (const float*)d_in[0];
  const float* ea      = (const float*)d_in[1];
  const float* W_emb   = (const float*)d_in[2];
  const float* b_emb   = (const float*)d_in[3];
  const float* W_temb  = (const float*)d_in[4];
  const float* b_temb  = (const float*)d_in[5];
  const float* W_tattr = (const float*)d_in[6];
  const float* b_tattr = (const float*)d_in[7];
  const float* W_gate  = (const float*)d_in[8];
  const float* b_gate  = (const float*)d_in[9];
  const float* W_l     = (const float*)d_in[10];
  const float* b_l     = (const float*)d_in[11];
  const float* W_r     = (const float*)d_in[12];
  const float* gamma   = (const float*)d_in[13];
  const float* beta    = (const float*)d_in[14];
  const int*   eidx    = (const int*)d_in[15];

  int N = in_sizes[0] / 128;
  int E = in_sizes[1] / 32;
  float* out = (float*)d_out;
  char* base = (char*)d_ws;

  // weight area: WembT 512 | WtaT 4096 | WteT 4096 | B1 16384 | Bta23 4096 | Bem 4096
  const size_t WB_SHORTS = 512 + 4096 + 4096 + 16384 + 4096 + 4096;

  size_t o = 0;
  auto take = [&](size_t b) { size_t r = o; o = (o + b + 255) & ~(size_t)255; return r; };
  size_t o_agg    = take((size_t)N * 128 * 4);
  size_t o_obf    = take((size_t)N * 128 * 2);
  size_t o_cnt    = take((size_t)N * 4);
  size_t o_rowptr = take((size_t)(N + 1) * 4);
  size_t o_wo     = take((size_t)N * 4);
  size_t o_src    = take((size_t)E * 4);
  size_t o_inv    = take((size_t)E * 4);
  size_t o_bn     = take(256 * 4);
  size_t o_wb     = take(WB_SHORTS * 2);
  size_t o_bgf    = take(128 * 4);
  size_t o_et     = take((size_t)E * 128 * 2);
  bool csr = (ws_size >= o);

  if (csr) {
    float* agg    = (float*)(base + o_agg);
    short* obf    = (short*)(base + o_obf);
    int*   cnt    = (int*)(base + o_cnt);
    int*   rowptr = (int*)(base + o_rowptr);
    int*   wo     = (int*)(base + o_wo);
    int*   src    = (int*)(base + o_src);
    int*   inv    = (int*)(base + o_inv);
    float* bn     = (float*)(base + o_bn);
    short* wb     = (short*)(base + o_wb);
    short* WembT  = wb;
    short* WtaT   = wb + 512;
    short* WteT   = wb + 4608;
    short* B1     = wb + 8704;
    short* Bta23  = wb + 25088;
    short* Bem    = wb + 29184;
    float* bgf    = (float*)(base + o_bgf);
    short* et     = (short*)(base + o_et);

    hipMemsetAsync(cnt, 0, (size_t)N * 4, stream);
    hipMemsetAsync(bn, 0, 256 * 4, stream);

    k_prep<<<64, 256, 0, stream>>>(W_emb, W_tattr, W_temb, W_gate,
                                   b_tattr, b_temb, b_gate,
                                   WembT, WtaT, WteT, B1, Bta23, Bem, bgf);
    k_count<<<512, 256, 0, stream>>>(eidx, cnt, E);
    k_scan<<<1, 1024, 0, stream>>>(cnt, rowptr, wo, N);
    k_fill<<<512, 256, 0, stream>>>(eidx, wo, src, inv, E);
    k_agg_gather<<<(N + 3) / 4, 256, 0, stream>>>(x, rowptr, src, agg, N);
    k_node_linear<<<(N + 31) / 32, 256, 0, stream>>>(x, agg, nullptr, W_l, b_l,
                                                     W_r, out, obf, N, 1);
    k_edge_gate_mfma<1><<<E / 64, 256, 0, stream>>>(
        ea, eidx, out, obf, WembT, b_emb, WteT, b_temb, WtaT, b_tattr,
        B1, Bta23, Bem, bgf, nullptr, et, inv, E);
    k_gate_gather<<<(N + 3) / 4, 256, 0, stream>>>(et, rowptr, out, N);
    k_bn_stats<<<512, 256, 0, stream>>>(out, nullptr, bn, N);
    k_finalize<<<2048, 256, 0, stream>>>(out, nullptr, bn, gamma, beta, N);
  } else {
    // --- fallback: atomic path (ws too small for CSR buffers) ---
    float* agg  = (float*)d_ws;
    float* cntf = agg + (size_t)N * 128;
    float* bn   = cntf + N;
    short* wb   = (short*)(bn + 256);
    short* WembT = wb;
    short* WtaT  = wb + 512;
    short* WteT  = wb + 4608;
    short* B1    = wb + 8704;
    short* Bta23 = wb + 25088;
    short* Bem   = wb + 29184;
    float* bgf   = (float*)(wb + WB_SHORTS + (WB_SHORTS & 1));

    size_t zero_bytes = ((size_t)N * 128 + N + 256) * sizeof(float);
    hipMemsetAsync(d_ws, 0, zero_bytes, stream);

    k_prep<<<64, 256, 0, stream>>>(W_emb, W_tattr, W_temb, W_gate,
                                   b_tattr, b_temb, b_gate,
                                   WembT, WtaT, WteT, B1, Bta23, Bem, bgf);
    k_aggregate<<<2048, 256, 0, stream>>>(x, eidx, agg, cntf, N, E);
    k_node_linear<<<(N + 31) / 32, 256, 0, stream>>>(x, agg, cntf, W_l, b_l,
                                                     W_r, out, nullptr, N, 0);
    k_edge_gate_mfma<0><<<E / 64, 256, 0, stream>>>(
        ea, eidx, out, nullptr, WembT, b_emb, WteT, b_temb, WtaT, b_tattr,
        B1, Bta23, Bem, bgf, agg, nullptr, nullptr, E);
    k_bn_stats<<<512, 256, 0, stream>>>(out, agg, bn, N);
    k_finalize<<<2048, 256, 0, stream>>>(out, agg, bn, gamma, beta, N);
  }
}